// Round 7
// baseline (424.253 us; speedup 1.0000x reference)
//
#include <hip/hip_runtime.h>
#include <math.h>

static const int NT = 50000, NDAT = 20000, NDEV = 4;
static const int EDT = 800000, EVT = 200000, ETT = 400000;

// scan geometry: 3 graphs x 25 tiles of 2048 (256 thr x 8 elems)
static const int SCAN_TILE = 2048, SCAN_NB = 25;

// ---------------- workspace layout (float offsets), liveness-aliased ----------------
static const size_t OFF_TASKS = 0;                   // 12,800,000  [NT,256] fp32; hsb (3.2M) aliases after gemm
static const size_t OFF_HS    = 12800000;            //  6,400,000  hs3 [NT,128] fp32 (written by gemm)
static const size_t OFF_RANK  = OFF_HS + 2560000;    //  1,400,000  ints (dead before gemm writes hs3)
static const size_t OFF_PERM1 = 19200000;            //  1,600,000  int2[EDT]
static const size_t OFF_PERM2 = 20800000;            //    400,000  int2[EVT]
static const size_t OFF_PERM3 = 21200000;            //    800,000  int2[ETT]
static const size_t OFF_DEG   = 23200000;            //    150,000  3 x NT ints
static const size_t OFF_RP    = 23350000;            //    150,003  3 x (NT+1) ints
static const size_t OFF_AS1   = 23500004;            //     80,000 (unused now)
static const size_t OFF_AD1   = 23580004;            //    200,000  as3 reuses
static const size_t OFF_AD2   = 23780004;            //    200,000  ad3 reuses
static const size_t OFF_HS2   = 23980004;            //        512
static const size_t OFF_AS2   = 23980516;            //         16
static const size_t OFF_QS1   = 23980532;            //         32
static const size_t OFF_QD1   = 23980564;            //         64
static const size_t OFF_P1    = 23980628;            //         32
static const size_t OFF_QS2   = 23980660;            //         32
static const size_t OFF_QD2   = 23980692;            //         64
static const size_t OFF_P2    = 23980756;            //         24
static const size_t OFF_P3    = 23980780;            //         16
static const size_t OFF_BSUM  = 23980796;            //        128 ints (75 used)
static const size_t OFF_W3HT  = 23980924;            //     16,384 (32768 ushorts, [128n][256k])
static const size_t OFF_W3LT  = 23997308;            //     16,384
static const size_t WS_TOTAL  = 24013692;            // floats (~96 MiB)

typedef short v8s __attribute__((ext_vector_type(8)));
typedef float v4f __attribute__((ext_vector_type(4)));

__device__ __forceinline__ float lrelu(float a) { return a > 0.f ? a : 0.2f * a; }
__device__ __forceinline__ unsigned short f2bf(float x) {
    unsigned int u = __float_as_uint(x);
    return (unsigned short)((u + 0x7FFFu + ((u >> 16) & 1u)) >> 16);
}
__device__ __forceinline__ float bf2f(unsigned short h) {
    return __uint_as_float(((unsigned int)h) << 16);
}
__device__ __forceinline__ void cvt_split(const float4& A, const float4& B, v8s& hi, v8s& lo) {
    union { unsigned short u[8]; v8s v; } H, L;
    float f[8] = {A.x, A.y, A.z, A.w, B.x, B.y, B.z, B.w};
    #pragma unroll
    for (int i = 0; i < 8; ++i) {
        unsigned short h = f2bf(f[i]);
        H.u[i] = h;
        L.u[i] = f2bf(f[i] - bf2f(h));
    }
    hi = H.v; lo = L.v;
}

// Q[k][h] = sum_c W[k*128 + h*32 + c] * A[h*32 + c], for all 7 small matrices
__global__ void k_proj_small(const float* Ws1, const float* As1,
                             const float* Wd1, const float* Ad1,
                             const float* We1, const float* Ae1,
                             const float* Ws2, const float* As2,
                             const float* Wd2, const float* Ad2,
                             const float* We2, const float* Ae2,
                             const float* We3, const float* Ae3,
                             float* Qs1, float* Qd1, float* P1,
                             float* Qs2, float* Qd2, float* P2, float* P3) {
    int t = threadIdx.x;
    const float *W, *A; float* O; int u;
    if      (t < 32)  { W = Ws1; A = As1; O = Qs1; u = t; }
    else if (t < 96)  { W = Wd1; A = Ad1; O = Qd1; u = t - 32; }
    else if (t < 128) { W = We1; A = Ae1; O = P1;  u = t - 96; }
    else if (t < 160) { W = Ws2; A = As2; O = Qs2; u = t - 128; }
    else if (t < 224) { W = Wd2; A = Ad2; O = Qd2; u = t - 160; }
    else if (t < 248) { W = We2; A = Ae2; O = P2;  u = t - 224; }
    else if (t < 264) { W = We3; A = Ae3; O = P3;  u = t - 248; }
    else return;
    int k = u >> 2, h = u & 3;
    float acc = 0.f;
    for (int c = 0; c < 32; ++c) acc += W[k * 128 + h * 32 + c] * A[h * 32 + c];
    O[k * 4 + h] = acc;
}

// one-time: split W3[256,128] into bf16 hi/lo, transposed to [128n][256k]
__global__ void k_w3split(const float* __restrict__ W3, unsigned short* __restrict__ hiT,
                          unsigned short* __restrict__ loT) {
    int idx = blockIdx.x * blockDim.x + threadIdx.x;
    if (idx >= 256 * 128) return;
    int k = idx >> 7, n = idx & 127;
    float x = W3[idx];
    unsigned short h = f2bf(x);
    hiT[n * 256 + k] = h;
    loT[n * 256 + k] = f2bf(x - bf2f(h));
}

// out[n][j] = sum_k x[n*K+k] * W[k*128+j]  (conv2's tiny hs2 only)
__global__ void k_linproj(const float* __restrict__ x, const float* __restrict__ W,
                          float* __restrict__ out, int N, int K) {
    int idx = blockIdx.x * blockDim.x + threadIdx.x;
    if (idx >= N * 128) return;
    int n = idx >> 7, j = idx & 127;
    float acc = 0.f;
    for (int k = 0; k < K; ++k) acc += x[n * K + k] * W[k * 128 + j];
    out[idx] = acc;
}

// out[n][h] = sum_k x[n*K+k] * Q[k*4+h]
__global__ void k_alpha(const float* __restrict__ x, const float* __restrict__ Q,
                        float* __restrict__ out, int N, int K) {
    int idx = blockIdx.x * blockDim.x + threadIdx.x;
    if (idx >= N * 4) return;
    int n = idx >> 2, h = idx & 3;
    float acc = 0.f;
    for (int k = 0; k < K; ++k) acc += x[n * K + k] * Q[k * 4 + h];
    out[idx] = acc;
}

// fused: adA[n][h] = x@Qa, adB[n][h] = x@Qb  (one pass over x_tasks)
__global__ void k_alpha2(const float* __restrict__ x, const float* __restrict__ Qa,
                         const float* __restrict__ Qb, float* __restrict__ oa,
                         float* __restrict__ ob, int N, int K) {
    int idx = blockIdx.x * blockDim.x + threadIdx.x;
    if (idx >= N * 4) return;
    int n = idx >> 2, h = idx & 3;
    float a = 0.f, b = 0.f;
    for (int k = 0; k < K; ++k) {
        float v = x[n * K + k];
        a += v * Qa[k * 4 + h];
        b += v * Qb[k * 4 + h];
    }
    oa[idx] = a; ob[idx] = b;
}

// fused: as3/ad3 from one float4-vectorized pass over hs3; also emits bf16 copy hsb
__global__ void k_alpha_from_h2(const float* __restrict__ hs, const float* __restrict__ As,
                                const float* __restrict__ Ad, float* __restrict__ oa,
                                float* __restrict__ ob, unsigned short* __restrict__ hsb,
                                int N) {
    int idx = blockIdx.x * blockDim.x + threadIdx.x;
    if (idx >= N * 4) return;
    int n = idx >> 2, h = idx & 3;
    const float* row = hs + (size_t)n * 128 + h * 32;
    unsigned short* brow = hsb + (size_t)n * 128 + h * 32;
    float a = 0.f, b = 0.f;
    #pragma unroll
    for (int c = 0; c < 32; c += 4) {
        float4 v = *reinterpret_cast<const float4*>(row + c);
        a += v.x * As[h * 32 + c]     + v.y * As[h * 32 + c + 1]
           + v.z * As[h * 32 + c + 2] + v.w * As[h * 32 + c + 3];
        b += v.x * Ad[h * 32 + c]     + v.y * Ad[h * 32 + c + 1]
           + v.z * Ad[h * 32 + c + 2] + v.w * Ad[h * 32 + c + 3];
        ushort4 pk;
        pk.x = f2bf(v.x); pk.y = f2bf(v.y); pk.z = f2bf(v.z); pk.w = f2bf(v.w);
        *reinterpret_cast<ushort4*>(brow + c) = pk;
    }
    oa[idx] = a; ob[idx] = b;
}

// degree histogram for all 3 graphs; also records each edge's rank within its dst
__global__ void k_hist(const int* __restrict__ dt, const int* __restrict__ vt,
                       const int* __restrict__ tt, int* __restrict__ deg,
                       int* __restrict__ rank) {
    int e = blockIdx.x * blockDim.x + threadIdx.x;
    if (e < EDT) rank[e] = atomicAdd(&deg[dt[EDT + e]], 1);
    else if (e < EDT + EVT) rank[e] = atomicAdd(&deg[NT + vt[EVT + (e - EDT)]], 1);
    else if (e < EDT + EVT + ETT) rank[e] = atomicAdd(&deg[2 * NT + tt[ETT + (e - EDT - EVT)]], 1);
}

// scan phase A: per-tile block reduce -> bsum[75]; coalesced int4 loads
__global__ __launch_bounds__(256) void k_scan_part(const int* __restrict__ deg,
                                                   int* __restrict__ bsum) {
    int b = blockIdx.x;
    int g = b / SCAN_NB, t = b % SCAN_NB;
    int base = t * SCAN_TILE + threadIdx.x * 8;
    const int* dg = deg + (size_t)g * NT;
    int s = 0;
    if (base + 8 <= NT) {
        int4 a = *reinterpret_cast<const int4*>(dg + base);
        int4 c = *reinterpret_cast<const int4*>(dg + base + 4);
        s = a.x + a.y + a.z + a.w + c.x + c.y + c.z + c.w;
    } else {
        for (int i = 0; i < 8; ++i) if (base + i < NT) s += dg[base + i];
    }
    __shared__ int red[256];
    red[threadIdx.x] = s;
    __syncthreads();
    for (int off = 128; off > 0; off >>= 1) {
        if (threadIdx.x < off) red[threadIdx.x] += red[threadIdx.x + off];
        __syncthreads();
    }
    if (threadIdx.x == 0) bsum[b] = red[0];
}

// scan phase B: one wave; exclusive-scan the 25 tile sums of each graph; write graph totals
__global__ void k_scan_bsum(int* __restrict__ bsum, int* __restrict__ rp) {
    int lane = threadIdx.x;
    for (int g = 0; g < 3; ++g) {
        int v = (lane < SCAN_NB) ? bsum[g * SCAN_NB + lane] : 0;
        int inc = v;
        #pragma unroll
        for (int off = 1; off < 32; off <<= 1) {
            int o = __shfl_up(inc, off, 32);
            if ((lane & 31) >= off) inc += o;
        }
        if (lane < SCAN_NB) bsum[g * SCAN_NB + lane] = inc - v;
        if (lane == SCAN_NB - 1) rp[(size_t)g * (NT + 1) + NT] = inc;
    }
}

// scan phase C: per-tile exclusive scan + tile offset; writes rp
__global__ __launch_bounds__(256) void k_scan_final(const int* __restrict__ deg,
                                                    const int* __restrict__ bsum,
                                                    int* __restrict__ rp) {
    int b = blockIdx.x;
    int g = b / SCAN_NB, t = b % SCAN_NB;
    int tid = threadIdx.x;
    int base = t * SCAN_TILE + tid * 8;
    const int* dg = deg + (size_t)g * NT;
    int* rpg = rp + (size_t)g * (NT + 1);
    int v[8];
    int s = 0;
    if (base + 8 <= NT) {
        int4 a = *reinterpret_cast<const int4*>(dg + base);
        int4 c = *reinterpret_cast<const int4*>(dg + base + 4);
        v[0] = a.x; v[1] = a.y; v[2] = a.z; v[3] = a.w;
        v[4] = c.x; v[5] = c.y; v[6] = c.z; v[7] = c.w;
        s = v[0] + v[1] + v[2] + v[3] + v[4] + v[5] + v[6] + v[7];
    } else {
        #pragma unroll
        for (int i = 0; i < 8; ++i) {
            v[i] = (base + i < NT) ? dg[base + i] : 0;
            s += v[i];
        }
    }
    __shared__ int sums[256];
    sums[tid] = s;
    __syncthreads();
    for (int off = 1; off < 256; off <<= 1) {
        int x = (tid >= off) ? sums[tid - off] : 0;
        __syncthreads();
        sums[tid] += x;
        __syncthreads();
    }
    int run = bsum[b] + (tid ? sums[tid - 1] : 0);
    #pragma unroll
    for (int i = 0; i < 8; ++i) {
        int idx = base + i;
        if (idx < NT) { rpg[idx] = run; run += v[i]; }
    }
}

// bucket pass: only {src, edge-id} (8B) per slot; no atomics (slot = rp[d] + rank[e])
__global__ void k_permute(const int* __restrict__ dt, const int* __restrict__ vt,
                          const int* __restrict__ tt, const int* __restrict__ rank,
                          const int* __restrict__ rp, int2* __restrict__ p1,
                          int2* __restrict__ p2, int2* __restrict__ p3) {
    int e = blockIdx.x * blockDim.x + threadIdx.x;
    if (e < EDT) {
        int d = dt[EDT + e];
        p1[rp[d] + rank[e]] = make_int2(dt[e], e);
    } else if (e < EDT + EVT) {
        int ee = e - EDT;
        int d = vt[EVT + ee];
        p2[rp[(NT + 1) + d] + rank[e]] = make_int2(vt[ee], ee);
    } else if (e < EDT + EVT + ETT) {
        int ee = e - EDT - EVT;
        int d = tt[ETT + ee];
        p3[rp[2 * (NT + 1) + d] + rank[e]] = make_int2(tt[ee], ee);
    }
}

// conv1 gather: recompute hs AND as from x_data (K=8) in-register; no message table.
// 32 lanes/dst (4 channels each); head h = lane>>3; edge loop unrolled x4 for MLP.
__global__ __launch_bounds__(256) void k_gather_c1(const int* __restrict__ rp,
                                                   const int2* __restrict__ perm,
                                                   const float* __restrict__ xd,
                                                   const float* __restrict__ Qs,
                                                   const float* __restrict__ Ws,
                                                   const float* __restrict__ P,
                                                   const float* __restrict__ ad_,
                                                   const float* __restrict__ ea,
                                                   const float* __restrict__ bias,
                                                   float* __restrict__ tasks) {
    int tid = threadIdx.x;
    int d = blockIdx.x * 8 + (tid >> 5);
    int lane = tid & 31;
    int h = lane >> 3;
    float Wc[8][4], Qk[8], Pk[8];
    #pragma unroll
    for (int k = 0; k < 8; ++k) {
        float4 wv = *reinterpret_cast<const float4*>(&Ws[k * 128 + lane * 4]);
        Wc[k][0] = wv.x; Wc[k][1] = wv.y; Wc[k][2] = wv.z; Wc[k][3] = wv.w;
        Qk[k] = Qs[k * 4 + h];
        Pk[k] = P[k * 4 + h];
    }
    float base = ad_[d * 4 + h];
    int i0 = rp[d], i1 = rp[d + 1];
    float a0 = 0.f, a1 = 0.f, a2 = 0.f, a3 = 0.f, den = 0.f;
    int i = i0;
    for (; i + 4 <= i1; i += 4) {
        int2 p0 = perm[i], p1 = perm[i + 1], p2 = perm[i + 2], p3 = perm[i + 3];
        float4 xa0 = *reinterpret_cast<const float4*>(&xd[(size_t)p0.x * 8]);
        float4 xb0 = *reinterpret_cast<const float4*>(&xd[(size_t)p0.x * 8 + 4]);
        float4 xa1 = *reinterpret_cast<const float4*>(&xd[(size_t)p1.x * 8]);
        float4 xb1 = *reinterpret_cast<const float4*>(&xd[(size_t)p1.x * 8 + 4]);
        float4 xa2 = *reinterpret_cast<const float4*>(&xd[(size_t)p2.x * 8]);
        float4 xb2 = *reinterpret_cast<const float4*>(&xd[(size_t)p2.x * 8 + 4]);
        float4 xa3 = *reinterpret_cast<const float4*>(&xd[(size_t)p3.x * 8]);
        float4 xb3 = *reinterpret_cast<const float4*>(&xd[(size_t)p3.x * 8 + 4]);
        float4 ea0 = *reinterpret_cast<const float4*>(&ea[(size_t)p0.y * 8]);
        float4 eb0 = *reinterpret_cast<const float4*>(&ea[(size_t)p0.y * 8 + 4]);
        float4 ea1 = *reinterpret_cast<const float4*>(&ea[(size_t)p1.y * 8]);
        float4 eb1 = *reinterpret_cast<const float4*>(&ea[(size_t)p1.y * 8 + 4]);
        float4 ea2 = *reinterpret_cast<const float4*>(&ea[(size_t)p2.y * 8]);
        float4 eb2 = *reinterpret_cast<const float4*>(&ea[(size_t)p2.y * 8 + 4]);
        float4 ea3 = *reinterpret_cast<const float4*>(&ea[(size_t)p3.y * 8]);
        float4 eb3 = *reinterpret_cast<const float4*>(&ea[(size_t)p3.y * 8 + 4]);
        #pragma unroll
        for (int u = 0; u < 4; ++u) {
            float4 XA = u == 0 ? xa0 : u == 1 ? xa1 : u == 2 ? xa2 : xa3;
            float4 XB = u == 0 ? xb0 : u == 1 ? xb1 : u == 2 ? xb2 : xb3;
            float4 EA = u == 0 ? ea0 : u == 1 ? ea1 : u == 2 ? ea2 : ea3;
            float4 EB = u == 0 ? eb0 : u == 1 ? eb1 : u == 2 ? eb2 : eb3;
            float x[8] = {XA.x, XA.y, XA.z, XA.w, XB.x, XB.y, XB.z, XB.w};
            float e[8] = {EA.x, EA.y, EA.z, EA.w, EB.x, EB.y, EB.z, EB.w};
            float l = base;
            #pragma unroll
            for (int k = 0; k < 8; ++k) l += x[k] * Qk[k];
            #pragma unroll
            for (int k = 0; k < 8; ++k) l += e[k] * Pk[k];
            float wgt = expf(lrelu(l));
            float m0 = 0.f, m1 = 0.f, m2 = 0.f, m3 = 0.f;
            #pragma unroll
            for (int k = 0; k < 8; ++k) {
                m0 += x[k] * Wc[k][0]; m1 += x[k] * Wc[k][1];
                m2 += x[k] * Wc[k][2]; m3 += x[k] * Wc[k][3];
            }
            a0 += wgt * m0; a1 += wgt * m1; a2 += wgt * m2; a3 += wgt * m3;
            den += wgt;
        }
    }
    for (; i < i1; ++i) {
        int2 p = perm[i];
        float4 XA = *reinterpret_cast<const float4*>(&xd[(size_t)p.x * 8]);
        float4 XB = *reinterpret_cast<const float4*>(&xd[(size_t)p.x * 8 + 4]);
        float4 EA = *reinterpret_cast<const float4*>(&ea[(size_t)p.y * 8]);
        float4 EB = *reinterpret_cast<const float4*>(&ea[(size_t)p.y * 8 + 4]);
        float x[8] = {XA.x, XA.y, XA.z, XA.w, XB.x, XB.y, XB.z, XB.w};
        float e[8] = {EA.x, EA.y, EA.z, EA.w, EB.x, EB.y, EB.z, EB.w};
        float l = base;
        #pragma unroll
        for (int k = 0; k < 8; ++k) l += x[k] * Qk[k];
        #pragma unroll
        for (int k = 0; k < 8; ++k) l += e[k] * Pk[k];
        float wgt = expf(lrelu(l));
        float m0 = 0.f, m1 = 0.f, m2 = 0.f, m3 = 0.f;
        #pragma unroll
        for (int k = 0; k < 8; ++k) {
            m0 += x[k] * Wc[k][0]; m1 += x[k] * Wc[k][1];
            m2 += x[k] * Wc[k][2]; m3 += x[k] * Wc[k][3];
        }
        a0 += wgt * m0; a1 += wgt * m1; a2 += wgt * m2; a3 += wgt * m3;
        den += wgt;
    }
    float4 b4 = *reinterpret_cast<const float4*>(&bias[lane * 4]);
    float r = 1.f / (den + 1e-16f);
    float4 o = make_float4(fmaxf(a0 * r + b4.x, 0.f), fmaxf(a1 * r + b4.y, 0.f),
                           fmaxf(a2 * r + b4.z, 0.f), fmaxf(a3 * r + b4.w, 0.f));
    *reinterpret_cast<float4*>(&tasks[(size_t)d * 256 + lane * 4]) = o;
}

template<int KE>
__device__ __forceinline__ void load_ea(const float* __restrict__ ea, int e, float* v) {
    if (KE == 8) {
        float4 a = *reinterpret_cast<const float4*>(ea + (size_t)e * 8);
        float4 b = *reinterpret_cast<const float4*>(ea + (size_t)e * 8 + 4);
        v[0] = a.x; v[1] = a.y; v[2] = a.z; v[3] = a.w;
        v[4] = b.x; v[5] = b.y; v[6] = b.z; v[7] = b.w;
    } else {
        float2 a = *reinterpret_cast<const float2*>(ea + (size_t)e * 6);
        float2 b = *reinterpret_cast<const float2*>(ea + (size_t)e * 6 + 2);
        float2 c = *reinterpret_cast<const float2*>(ea + (size_t)e * 6 + 4);
        v[0] = a.x; v[1] = a.y; v[2] = b.x; v[3] = b.y; v[4] = c.x; v[5] = c.y;
    }
}

// conv2 gather (message table = 4 rows, cache-resident): recompute attention, unroll x4
template<int KE>
__global__ __launch_bounds__(256) void k_gather12(const int* __restrict__ rp,
                                                  const int2* __restrict__ perm,
                                                  const float* __restrict__ as_,
                                                  const float* __restrict__ ad_,
                                                  const float* __restrict__ P,
                                                  const float* __restrict__ ea,
                                                  const float* __restrict__ hs,
                                                  const float* __restrict__ bias,
                                                  float* __restrict__ tasks, int cbase) {
    int tid = threadIdx.x;
    int d = blockIdx.x * 8 + (tid >> 5);
    int lane = tid & 31;
    int h = lane >> 3;
    float Pk[KE];
    #pragma unroll
    for (int k = 0; k < KE; ++k) Pk[k] = P[k * 4 + h];
    float base = ad_[d * 4 + h];
    int i0 = rp[d], i1 = rp[d + 1];
    float ax = 0.f, ay = 0.f, az = 0.f, aw = 0.f, den = 0.f;
    int i = i0;
    for (; i + 4 <= i1; i += 4) {
        int2 p0 = perm[i], p1 = perm[i + 1], p2 = perm[i + 2], p3 = perm[i + 3];
        float e0[KE], e1[KE], e2[KE], e3[KE];
        load_ea<KE>(ea, p0.y, e0); load_ea<KE>(ea, p1.y, e1);
        load_ea<KE>(ea, p2.y, e2); load_ea<KE>(ea, p3.y, e3);
        float l0 = base + as_[p0.x * 4 + h];
        float l1 = base + as_[p1.x * 4 + h];
        float l2 = base + as_[p2.x * 4 + h];
        float l3 = base + as_[p3.x * 4 + h];
        float4 v0 = *reinterpret_cast<const float4*>(&hs[(size_t)p0.x * 128 + lane * 4]);
        float4 v1 = *reinterpret_cast<const float4*>(&hs[(size_t)p1.x * 128 + lane * 4]);
        float4 v2 = *reinterpret_cast<const float4*>(&hs[(size_t)p2.x * 128 + lane * 4]);
        float4 v3 = *reinterpret_cast<const float4*>(&hs[(size_t)p3.x * 128 + lane * 4]);
        #pragma unroll
        for (int k = 0; k < KE; ++k) {
            l0 += e0[k] * Pk[k]; l1 += e1[k] * Pk[k];
            l2 += e2[k] * Pk[k]; l3 += e3[k] * Pk[k];
        }
        float w0 = expf(lrelu(l0)), w1 = expf(lrelu(l1));
        float w2 = expf(lrelu(l2)), w3 = expf(lrelu(l3));
        ax += v0.x * w0 + v1.x * w1 + v2.x * w2 + v3.x * w3;
        ay += v0.y * w0 + v1.y * w1 + v2.y * w2 + v3.y * w3;
        az += v0.z * w0 + v1.z * w1 + v2.z * w2 + v3.z * w3;
        aw += v0.w * w0 + v1.w * w1 + v2.w * w2 + v3.w * w3;
        den += w0 + w1 + w2 + w3;
    }
    for (; i < i1; ++i) {
        int2 p = perm[i];
        float ev[KE];
        load_ea<KE>(ea, p.y, ev);
        float l = base + as_[p.x * 4 + h];
        #pragma unroll
        for (int k = 0; k < KE; ++k) l += ev[k] * Pk[k];
        float w = expf(lrelu(l));
        float4 v = *reinterpret_cast<const float4*>(&hs[(size_t)p.x * 128 + lane * 4]);
        ax += v.x * w; ay += v.y * w; az += v.z * w; aw += v.w * w;
        den += w;
    }
    float4 b4 = *reinterpret_cast<const float4*>(&bias[lane * 4]);
    float r = 1.f / (den + 1e-16f);
    float4 o = make_float4(fmaxf(ax * r + b4.x, 0.f), fmaxf(ay * r + b4.y, 0.f),
                           fmaxf(az * r + b4.z, 0.f), fmaxf(aw * r + b4.w, 0.f));
    *reinterpret_cast<float4*>(&tasks[(size_t)d * 256 + cbase + lane * 4]) = o;
}

// conv3 gather: bf16 messages, head-per-lane (h=lane>>3, channels 4*(lane&7)..+3),
// per-head softmax + self-loop; head-mean via shfl_xor; +b3, relu fused.
__global__ __launch_bounds__(256) void k_gather_c3(const int* __restrict__ rp,
                                                   const int2* __restrict__ perm,
                                                   const float* __restrict__ as3,
                                                   const float* __restrict__ ad3,
                                                   const float* __restrict__ P3,
                                                   const float* __restrict__ ea,
                                                   const unsigned short* __restrict__ hsb,
                                                   const float* __restrict__ b3,
                                                   float* __restrict__ out) {
    int tid = threadIdx.x;
    int d = blockIdx.x * 8 + (tid >> 5);
    int lane = tid & 31;
    int h = lane >> 3;
    int c0 = (lane & 7) * 4;
    float Pk[4];
    #pragma unroll
    for (int k = 0; k < 4; ++k) Pk[k] = P3[k * 4 + h];
    float adv = ad3[d * 4 + h];
    int i0 = rp[d], i1 = rp[d + 1];
    float a0 = 0.f, a1 = 0.f, a2 = 0.f, a3 = 0.f, den = 0.f, aes = 0.f;
    int i = i0;
    for (; i + 4 <= i1; i += 4) {
        int2 p0 = perm[i], p1 = perm[i + 1], p2 = perm[i + 2], p3 = perm[i + 3];
        float s0 = as3[(size_t)p0.x * 4 + h], s1 = as3[(size_t)p1.x * 4 + h];
        float s2 = as3[(size_t)p2.x * 4 + h], s3 = as3[(size_t)p3.x * 4 + h];
        float4 q0 = *reinterpret_cast<const float4*>(&ea[(size_t)p0.y * 4]);
        float4 q1 = *reinterpret_cast<const float4*>(&ea[(size_t)p1.y * 4]);
        float4 q2 = *reinterpret_cast<const float4*>(&ea[(size_t)p2.y * 4]);
        float4 q3 = *reinterpret_cast<const float4*>(&ea[(size_t)p3.y * 4]);
        ushort4 m0 = *reinterpret_cast<const ushort4*>(&hsb[(size_t)p0.x * 128 + h * 32 + c0]);
        ushort4 m1 = *reinterpret_cast<const ushort4*>(&hsb[(size_t)p1.x * 128 + h * 32 + c0]);
        ushort4 m2 = *reinterpret_cast<const ushort4*>(&hsb[(size_t)p2.x * 128 + h * 32 + c0]);
        ushort4 m3 = *reinterpret_cast<const ushort4*>(&hsb[(size_t)p3.x * 128 + h * 32 + c0]);
        float ae0 = q0.x * Pk[0] + q0.y * Pk[1] + q0.z * Pk[2] + q0.w * Pk[3];
        float ae1 = q1.x * Pk[0] + q1.y * Pk[1] + q1.z * Pk[2] + q1.w * Pk[3];
        float ae2 = q2.x * Pk[0] + q2.y * Pk[1] + q2.z * Pk[2] + q2.w * Pk[3];
        float ae3 = q3.x * Pk[0] + q3.y * Pk[1] + q3.z * Pk[2] + q3.w * Pk[3];
        float w0 = expf(lrelu(s0 + adv + ae0));
        float w1 = expf(lrelu(s1 + adv + ae1));
        float w2 = expf(lrelu(s2 + adv + ae2));
        float w3 = expf(lrelu(s3 + adv + ae3));
        a0 += w0 * bf2f(m0.x) + w1 * bf2f(m1.x) + w2 * bf2f(m2.x) + w3 * bf2f(m3.x);
        a1 += w0 * bf2f(m0.y) + w1 * bf2f(m1.y) + w2 * bf2f(m2.y) + w3 * bf2f(m3.y);
        a2 += w0 * bf2f(m0.z) + w1 * bf2f(m1.z) + w2 * bf2f(m2.z) + w3 * bf2f(m3.z);
        a3 += w0 * bf2f(m0.w) + w1 * bf2f(m1.w) + w2 * bf2f(m2.w) + w3 * bf2f(m3.w);
        den += w0 + w1 + w2 + w3;
        aes += ae0 + ae1 + ae2 + ae3;
    }
    for (; i < i1; ++i) {
        int2 p = perm[i];
        float s = as3[(size_t)p.x * 4 + h];
        float4 q = *reinterpret_cast<const float4*>(&ea[(size_t)p.y * 4]);
        ushort4 m = *reinterpret_cast<const ushort4*>(&hsb[(size_t)p.x * 128 + h * 32 + c0]);
        float ae = q.x * Pk[0] + q.y * Pk[1] + q.z * Pk[2] + q.w * Pk[3];
        float w = expf(lrelu(s + adv + ae));
        a0 += w * bf2f(m.x); a1 += w * bf2f(m.y);
        a2 += w * bf2f(m.z); a3 += w * bf2f(m.w);
        den += w; aes += ae;
    }
    // self loop (mean edge-attr logit), per head
    float cnt = (float)(i1 - i0);
    float mloop = aes / fmaxf(cnt, 1.f);
    float exl = expf(lrelu(as3[(size_t)d * 4 + h] + adv + mloop));
    ushort4 md = *reinterpret_cast<const ushort4*>(&hsb[(size_t)d * 128 + h * 32 + c0]);
    float rden = 1.f / (den + exl + 1e-16f);
    float p0 = (a0 + exl * bf2f(md.x)) * rden;
    float p1 = (a1 + exl * bf2f(md.y)) * rden;
    float p2 = (a2 + exl * bf2f(md.z)) * rden;
    float p3 = (a3 + exl * bf2f(md.w)) * rden;
    // head-mean across lanes {l, l^8, l^16, l^24}
    p0 += __shfl_xor(p0, 8, 32); p0 += __shfl_xor(p0, 16, 32);
    p1 += __shfl_xor(p1, 8, 32); p1 += __shfl_xor(p1, 16, 32);
    p2 += __shfl_xor(p2, 8, 32); p2 += __shfl_xor(p2, 16, 32);
    p3 += __shfl_xor(p3, 8, 32); p3 += __shfl_xor(p3, 16, 32);
    if ((lane >> 3) == 0) {
        float4 o;
        o.x = fmaxf(0.25f * p0 + b3[c0 + 0], 0.f);
        o.y = fmaxf(0.25f * p1 + b3[c0 + 1], 0.f);
        o.z = fmaxf(0.25f * p2 + b3[c0 + 2], 0.f);
        o.w = fmaxf(0.25f * p3 + b3[c0 + 3], 0.f);
        *reinterpret_cast<float4*>(&out[(size_t)d * 32 + c0]) = o;
    }
}

// hs3 = tasks[50000,256] @ W3[256,128] via bf16 split MFMA (Ah*Bh + Ah*Bl + Al*Bh)
__global__ __launch_bounds__(256, 2) void k_gemm_mfma(const float* __restrict__ T,
                                                      const unsigned short* __restrict__ w3hT,
                                                      const unsigned short* __restrict__ w3lT,
                                                      float* __restrict__ outp) {
    __shared__ uint4 sB[2][2048];      // [hi/lo][128 cols x 16 chunks], 64 KiB
    int tid = threadIdx.x;
    int lane = tid & 63;
    int wid = tid >> 6;
    int arow = lane & 15;
    int kgrp = lane >> 4;
    int s0 = blockIdx.x * 8 + wid * 2;
    int ss0 = s0 < 3125 ? s0 : 3124;
    int ss1 = (s0 + 1) < 3125 ? (s0 + 1) : 3124;
    const uint4* w3h4 = reinterpret_cast<const uint4*>(w3hT);
    const uint4* w3l4 = reinterpret_cast<const uint4*>(w3lT);

    v4f acc[2][8];
    #pragma unroll
    for (int sp = 0; sp < 2; ++sp)
        #pragma unroll
        for (int nt = 0; nt < 8; ++nt) acc[sp][nt] = (v4f)0.f;

    #pragma unroll
    for (int kt = 0; kt < 2; ++kt) {
        __syncthreads();
        float4 a0[8], a1[8];
        const float* Ta0 = T + (size_t)(ss0 * 16 + arow) * 256 + kt * 128 + kgrp * 8;
        const float* Ta1 = T + (size_t)(ss1 * 16 + arow) * 256 + kt * 128 + kgrp * 8;
        #pragma unroll
        for (int kc = 0; kc < 4; ++kc) {
            a0[kc * 2]     = *reinterpret_cast<const float4*>(Ta0 + kc * 32);
            a0[kc * 2 + 1] = *reinterpret_cast<const float4*>(Ta0 + kc * 32 + 4);
            a1[kc * 2]     = *reinterpret_cast<const float4*>(Ta1 + kc * 32);
            a1[kc * 2 + 1] = *reinterpret_cast<const float4*>(Ta1 + kc * 32 + 4);
        }
        #pragma unroll
        for (int it = 0; it < 8; ++it) {
            int c = it * 256 + tid;
            int n = c >> 4, ch = c & 15;
            int gi = n * 32 + kt * 16 + ch;
            int li = n * 16 + (ch ^ (n & 7));
            sB[0][li] = w3h4[gi];
            sB[1][li] = w3l4[gi];
        }
        __syncthreads();
        #pragma unroll
        for (int kc = 0; kc < 4; ++kc) {
            v8s ah0, al0, ah1, al1;
            cvt_split(a0[kc * 2], a0[kc * 2 + 1], ah0, al0);
            cvt_split(a1[kc * 2], a1[kc * 2 + 1], ah1, al1);
            #pragma unroll
            for (int nt = 0; nt < 8; ++nt) {
                int col = nt * 16 + arow;
                int ch = kc * 4 + kgrp;
                int li = col * 16 + (ch ^ (col & 7));
                v8s bh = *reinterpret_cast<const v8s*>(&sB[0][li]);
                v8s bl = *reinterpret_cast<const v8s*>(&sB[1][li]);
                acc[0][nt] = __builtin_amdgcn_mfma_f32_16x16x32_bf16(ah0, bh, acc[0][nt], 0, 0, 0);
                acc[0][nt] = __builtin_amdgcn_mfma_f32_16x16x32_bf16(ah0, bl, acc[0][nt], 0, 0, 0);
                acc[0][nt] = __builtin_amdgcn_mfma_f32_16x16x32_bf16(al0, bh, acc[0][nt], 0, 0, 0);
                acc[1][nt] = __builtin_amdgcn_mfma_f32_16x16x32_bf16(ah1, bh, acc[1][nt], 0, 0, 0);
                acc[1][nt] = __builtin_amdgcn_mfma_f32_16x16x32_bf16(ah1, bl, acc[1][nt], 0, 0, 0);
                acc[1][nt] = __builtin_amdgcn_mfma_f32_16x16x32_bf16(al1, bh, acc[1][nt], 0, 0, 0);
            }
        }
    }
    if (s0 < 3125) {
        #pragma unroll
        for (int nt = 0; nt < 8; ++nt)
            #pragma unroll
            for (int i = 0; i < 4; ++i)
                outp[(size_t)(s0 * 16 + kgrp * 4 + i) * 128 + nt * 16 + arow] = acc[0][nt][i];
    }
    if (s0 + 1 < 3125) {
        #pragma unroll
        for (int nt = 0; nt < 8; ++nt)
            #pragma unroll
            for (int i = 0; i < 4; ++i)
                outp[(size_t)((s0 + 1) * 16 + kgrp * 4 + i) * 128 + nt * 16 + arow] = acc[1][nt][i];
    }
}

extern "C" void kernel_launch(void* const* d_in, const int* in_sizes, int n_in,
                              void* d_out, int out_size, void* d_ws, size_t ws_size,
                              hipStream_t stream) {
    const float* x_data  = (const float*)d_in[0];
    const float* x_tasks = (const float*)d_in[1];
    const float* x_dev   = (const float*)d_in[2];
    const int*   ei_dt   = (const int*)d_in[3];
    const float* ea_dt   = (const float*)d_in[4];
    const int*   ei_vt   = (const int*)d_in[5];
    const float* ea_vt   = (const float*)d_in[6];
    const int*   ei_tt   = (const int*)d_in[7];
    const float* ea_tt   = (const float*)d_in[8];
    const float* Ws1 = (const float*)d_in[9];  const float* Wd1 = (const float*)d_in[10];
    const float* We1 = (const float*)d_in[11]; const float* As1 = (const float*)d_in[12];
    const float* Ad1 = (const float*)d_in[13]; const float* Ae1 = (const float*)d_in[14];
    const float* b1  = (const float*)d_in[15];
    const float* Ws2 = (const float*)d_in[16]; const float* Wd2 = (const float*)d_in[17];
    const float* We2 = (const float*)d_in[18]; const float* As2 = (const float*)d_in[19];
    const float* Ad2 = (const float*)d_in[20]; const float* Ae2 = (const float*)d_in[21];
    const float* b2  = (const float*)d_in[22];
    const float* W3  = (const float*)d_in[23]; const float* We3 = (const float*)d_in[24];
    const float* As3 = (const float*)d_in[25]; const float* Ad3 = (const float*)d_in[26];
    const float* Ae3 = (const float*)d_in[27]; const float* b3  = (const float*)d_in[28];

    if (ws_size < WS_TOTAL * sizeof(float)) return;

    float* w = (float*)d_ws;
    float* tasks = w + OFF_TASKS;
    unsigned short* hsb = (unsigned short*)(w + OFF_TASKS);   // aliases tasks (dead after gemm)
    float* hs    = w + OFF_HS;                                // hs3
    int*   rank  = (int*)(w + OFF_RANK);
    int2*  perm1 = (int2*)(w + OFF_PERM1);
    int2*  perm2 = (int2*)(w + OFF_PERM2);
    int2*  perm3 = (int2*)(w + OFF_PERM3);
    int*   deg   = (int*)(w + OFF_DEG);
    int*   rp    = (int*)(w + OFF_RP);
    int*   bsum  = (int*)(w + OFF_BSUM);
    unsigned short* w3hT = (unsigned short*)(w + OFF_W3HT);
    unsigned short* w3lT = (unsigned short*)(w + OFF_W3LT);
    float* ad1 = w + OFF_AD1; float* as3 = w + OFF_AD1;   // as3 aliases ad1
    float* ad2 = w + OFF_AD2; float* ad3 = w + OFF_AD2;   // ad3 aliases ad2
    float* hs2 = w + OFF_HS2; float* as2 = w + OFF_AS2;
    float* Qs1 = w + OFF_QS1; float* Qd1 = w + OFF_QD1; float* P1 = w + OFF_P1;
    float* Qs2 = w + OFF_QS2; float* Qd2 = w + OFF_QD2; float* P2 = w + OFF_P2;
    float* P3  = w + OFF_P3;
    float* out = (float*)d_out;

    dim3 B(256);
    #define GRID(n) dim3((unsigned)(((n) + 255) / 256))

    // CSR prep: zero degrees, histogram(+rank), hierarchical scan, atomic-free permute
    hipMemsetAsync(deg, 0, 3 * NT * sizeof(int), stream);
    k_proj_small<<<1, 320, 0, stream>>>(Ws1, As1, Wd1, Ad1, We1, Ae1,
                                        Ws2, As2, Wd2, Ad2, We2, Ae2, We3, Ae3,
                                        Qs1, Qd1, P1, Qs2, Qd2, P2, P3);
    k_w3split<<<GRID(256 * 128), B, 0, stream>>>(W3, w3hT, w3lT);
    k_hist<<<GRID(EDT + EVT + ETT), B, 0, stream>>>(ei_dt, ei_vt, ei_tt, deg, rank);
    k_scan_part<<<dim3(3 * SCAN_NB), B, 0, stream>>>(deg, bsum);
    k_scan_bsum<<<1, 64, 0, stream>>>(bsum, rp);
    k_scan_final<<<dim3(3 * SCAN_NB), B, 0, stream>>>(deg, bsum, rp);
    k_permute<<<GRID(EDT + EVT + ETT), B, 0, stream>>>(ei_dt, ei_vt, ei_tt, rank, rp,
                                                       perm1, perm2, perm3);

    // conv1 + conv2 inputs
    k_alpha2<<<GRID(NT * 4), B, 0, stream>>>(x_tasks, Qd1, Qd2, ad1, ad2, NT, 16);
    k_linproj<<<GRID(NDEV * 128), B, 0, stream>>>(x_dev, Ws2, hs2, NDEV, 8);
    k_alpha<<<GRID(NDEV * 4), B, 0, stream>>>(x_dev, Qs2, as2, NDEV, 8);
    // gathers (conv1 recomputes hs/as from x_data; bias+relu fused)
    k_gather_c1<<<dim3(NT / 8), B, 0, stream>>>(rp, perm1, x_data, Qs1, Ws1, P1,
                                                ad1, ea_dt, b1, tasks);
    k_gather12<6><<<dim3(NT / 8), B, 0, stream>>>(rp + (NT + 1), perm2, as2, ad2, P2, ea_vt,
                                                  hs2, b2, tasks, 128);

    // conv3: tasks -> tasks
    k_gemm_mfma<<<dim3(391), dim3(256), 0, stream>>>(tasks, w3hT, w3lT, hs);
    k_alpha_from_h2<<<GRID(NT * 4), B, 0, stream>>>(hs, As3, Ad3, as3, ad3, hsb, NT);
    k_gather_c3<<<dim3(NT / 8), B, 0, stream>>>(rp + 2 * (NT + 1), perm3, as3, ad3, P3, ea_tt,
                                                hsb, b3, out);
    #undef GRID
}

// Round 8
// 308.114 us; speedup vs baseline: 1.3769x; 1.3769x over previous
//
#include <hip/hip_runtime.h>
#include <math.h>

static const int NT = 50000, NDAT = 20000, NDEV = 4;
static const int EDT = 800000, EVT = 200000, ETT = 400000;

// scan geometry: 3 graphs x 25 tiles of 2048 (256 thr x 8 elems)
static const int SCAN_TILE = 2048, SCAN_NB = 25;

// ---------------- workspace layout (float offsets), liveness-aliased ----------------
static const size_t OFF_TASKS = 0;                   // 12,800,000  [NT,256] fp32; hsb3 (3.2M) aliases after gemm
static const size_t OFF_HS    = 12800000;            //  6,400,000  hs3 [NT,128] fp32 (written by gemm)
static const size_t OFF_RANK  = OFF_HS + 2560000;    //  1,400,000  ints; hsb1 (1.28M) aliases after permute
static const size_t OFF_PERM1 = 19200000;            //  1,600,000  int2[EDT]
static const size_t OFF_PERM2 = 20800000;            //    400,000  int2[EVT]
static const size_t OFF_PERM3 = 21200000;            //    800,000  int2[ETT]
static const size_t OFF_DEG   = 23200000;            //    150,000  3 x NT ints
static const size_t OFF_RP    = 23350000;            //    150,003  3 x (NT+1) ints
static const size_t OFF_AS1   = 23500004;            //     80,000
static const size_t OFF_AD1   = 23580004;            //    200,000  as3 reuses
static const size_t OFF_AD2   = 23780004;            //    200,000  ad3 reuses
static const size_t OFF_HS2   = 23980004;            //        512
static const size_t OFF_AS2   = 23980516;            //         16
static const size_t OFF_QS1   = 23980532;            //         32
static const size_t OFF_QD1   = 23980564;            //         64
static const size_t OFF_P1    = 23980628;            //         32
static const size_t OFF_QS2   = 23980660;            //         32
static const size_t OFF_QD2   = 23980692;            //         64
static const size_t OFF_P2    = 23980756;            //         24
static const size_t OFF_P3    = 23980780;            //         16
static const size_t OFF_BSUM  = 23980796;            //        128 ints (75 used)
static const size_t OFF_W3HT  = 23980924;            //     16,384 (32768 ushorts, [128n][256k])
static const size_t OFF_W3LT  = 23997308;            //     16,384
static const size_t WS_TOTAL  = 24013692;            // floats (~96 MiB)

typedef short v8s __attribute__((ext_vector_type(8)));
typedef float v4f __attribute__((ext_vector_type(4)));

__device__ __forceinline__ float lrelu(float a) { return a > 0.f ? a : 0.2f * a; }
__device__ __forceinline__ unsigned short f2bf(float x) {
    unsigned int u = __float_as_uint(x);
    return (unsigned short)((u + 0x7FFFu + ((u >> 16) & 1u)) >> 16);
}
__device__ __forceinline__ float bf2f(unsigned short h) {
    return __uint_as_float(((unsigned int)h) << 16);
}
__device__ __forceinline__ void cvt_split(const float4& A, const float4& B, v8s& hi, v8s& lo) {
    union { unsigned short u[8]; v8s v; } H, L;
    float f[8] = {A.x, A.y, A.z, A.w, B.x, B.y, B.z, B.w};
    #pragma unroll
    for (int i = 0; i < 8; ++i) {
        unsigned short h = f2bf(f[i]);
        H.u[i] = h;
        L.u[i] = f2bf(f[i] - bf2f(h));
    }
    hi = H.v; lo = L.v;
}

// Q[k][h] = sum_c W[k*128 + h*32 + c] * A[h*32 + c], for all 7 small matrices
__global__ void k_proj_small(const float* Ws1, const float* As1,
                             const float* Wd1, const float* Ad1,
                             const float* We1, const float* Ae1,
                             const float* Ws2, const float* As2,
                             const float* Wd2, const float* Ad2,
                             const float* We2, const float* Ae2,
                             const float* We3, const float* Ae3,
                             float* Qs1, float* Qd1, float* P1,
                             float* Qs2, float* Qd2, float* P2, float* P3) {
    int t = threadIdx.x;
    const float *W, *A; float* O; int u;
    if      (t < 32)  { W = Ws1; A = As1; O = Qs1; u = t; }
    else if (t < 96)  { W = Wd1; A = Ad1; O = Qd1; u = t - 32; }
    else if (t < 128) { W = We1; A = Ae1; O = P1;  u = t - 96; }
    else if (t < 160) { W = Ws2; A = As2; O = Qs2; u = t - 128; }
    else if (t < 224) { W = Wd2; A = Ad2; O = Qd2; u = t - 160; }
    else if (t < 248) { W = We2; A = Ae2; O = P2;  u = t - 224; }
    else if (t < 264) { W = We3; A = Ae3; O = P3;  u = t - 248; }
    else return;
    int k = u >> 2, h = u & 3;
    float acc = 0.f;
    for (int c = 0; c < 32; ++c) acc += W[k * 128 + h * 32 + c] * A[h * 32 + c];
    O[k * 4 + h] = acc;
}

// one-time: split W3[256,128] into bf16 hi/lo, transposed to [128n][256k]
__global__ void k_w3split(const float* __restrict__ W3, unsigned short* __restrict__ hiT,
                          unsigned short* __restrict__ loT) {
    int idx = blockIdx.x * blockDim.x + threadIdx.x;
    if (idx >= 256 * 128) return;
    int k = idx >> 7, n = idx & 127;
    float x = W3[idx];
    unsigned short h = f2bf(x);
    hiT[n * 256 + k] = h;
    loT[n * 256 + k] = f2bf(x - bf2f(h));
}

// out[n][j] = sum_k x[n*K+k] * W[k*128+j]  (conv2's tiny hs2, fp32)
__global__ void k_linproj(const float* __restrict__ x, const float* __restrict__ W,
                          float* __restrict__ out, int N, int K) {
    int idx = blockIdx.x * blockDim.x + threadIdx.x;
    if (idx >= N * 128) return;
    int n = idx >> 7, j = idx & 127;
    float acc = 0.f;
    for (int k = 0; k < K; ++k) acc += x[n * K + k] * W[k * 128 + j];
    out[idx] = acc;
}

// conv1's message table, bf16: hsb[n][j] = bf16(sum_k x[n*K+k] * W[k*128+j])
__global__ void k_linproj_bf(const float* __restrict__ x, const float* __restrict__ W,
                             unsigned short* __restrict__ out, int N, int K) {
    int idx = blockIdx.x * blockDim.x + threadIdx.x;
    if (idx >= N * 128) return;
    int n = idx >> 7, j = idx & 127;
    float acc = 0.f;
    for (int k = 0; k < K; ++k) acc += x[n * K + k] * W[k * 128 + j];
    out[idx] = f2bf(acc);
}

// out[n][h] = sum_k x[n*K+k] * Q[k*4+h]
__global__ void k_alpha(const float* __restrict__ x, const float* __restrict__ Q,
                        float* __restrict__ out, int N, int K) {
    int idx = blockIdx.x * blockDim.x + threadIdx.x;
    if (idx >= N * 4) return;
    int n = idx >> 2, h = idx & 3;
    float acc = 0.f;
    for (int k = 0; k < K; ++k) acc += x[n * K + k] * Q[k * 4 + h];
    out[idx] = acc;
}

// fused: adA[n][h] = x@Qa, adB[n][h] = x@Qb  (one pass over x_tasks)
__global__ void k_alpha2(const float* __restrict__ x, const float* __restrict__ Qa,
                         const float* __restrict__ Qb, float* __restrict__ oa,
                         float* __restrict__ ob, int N, int K) {
    int idx = blockIdx.x * blockDim.x + threadIdx.x;
    if (idx >= N * 4) return;
    int n = idx >> 2, h = idx & 3;
    float a = 0.f, b = 0.f;
    for (int k = 0; k < K; ++k) {
        float v = x[n * K + k];
        a += v * Qa[k * 4 + h];
        b += v * Qb[k * 4 + h];
    }
    oa[idx] = a; ob[idx] = b;
}

// fused: as3/ad3 from one float4-vectorized pass over hs3; also emits bf16 copy hsb
__global__ void k_alpha_from_h2(const float* __restrict__ hs, const float* __restrict__ As,
                                const float* __restrict__ Ad, float* __restrict__ oa,
                                float* __restrict__ ob, unsigned short* __restrict__ hsb,
                                int N) {
    int idx = blockIdx.x * blockDim.x + threadIdx.x;
    if (idx >= N * 4) return;
    int n = idx >> 2, h = idx & 3;
    const float* row = hs + (size_t)n * 128 + h * 32;
    unsigned short* brow = hsb + (size_t)n * 128 + h * 32;
    float a = 0.f, b = 0.f;
    #pragma unroll
    for (int c = 0; c < 32; c += 4) {
        float4 v = *reinterpret_cast<const float4*>(row + c);
        a += v.x * As[h * 32 + c]     + v.y * As[h * 32 + c + 1]
           + v.z * As[h * 32 + c + 2] + v.w * As[h * 32 + c + 3];
        b += v.x * Ad[h * 32 + c]     + v.y * Ad[h * 32 + c + 1]
           + v.z * Ad[h * 32 + c + 2] + v.w * Ad[h * 32 + c + 3];
        ushort4 pk;
        pk.x = f2bf(v.x); pk.y = f2bf(v.y); pk.z = f2bf(v.z); pk.w = f2bf(v.w);
        *reinterpret_cast<ushort4*>(brow + c) = pk;
    }
    oa[idx] = a; ob[idx] = b;
}

// degree histogram for all 3 graphs; also records each edge's rank within its dst
__global__ void k_hist(const int* __restrict__ dt, const int* __restrict__ vt,
                       const int* __restrict__ tt, int* __restrict__ deg,
                       int* __restrict__ rank) {
    int e = blockIdx.x * blockDim.x + threadIdx.x;
    if (e < EDT) rank[e] = atomicAdd(&deg[dt[EDT + e]], 1);
    else if (e < EDT + EVT) rank[e] = atomicAdd(&deg[NT + vt[EVT + (e - EDT)]], 1);
    else if (e < EDT + EVT + ETT) rank[e] = atomicAdd(&deg[2 * NT + tt[ETT + (e - EDT - EVT)]], 1);
}

// scan phase A: per-tile block reduce -> bsum[75]; coalesced int4 loads
__global__ __launch_bounds__(256) void k_scan_part(const int* __restrict__ deg,
                                                   int* __restrict__ bsum) {
    int b = blockIdx.x;
    int g = b / SCAN_NB, t = b % SCAN_NB;
    int base = t * SCAN_TILE + threadIdx.x * 8;
    const int* dg = deg + (size_t)g * NT;
    int s = 0;
    if (base + 8 <= NT) {
        int4 a = *reinterpret_cast<const int4*>(dg + base);
        int4 c = *reinterpret_cast<const int4*>(dg + base + 4);
        s = a.x + a.y + a.z + a.w + c.x + c.y + c.z + c.w;
    } else {
        for (int i = 0; i < 8; ++i) if (base + i < NT) s += dg[base + i];
    }
    __shared__ int red[256];
    red[threadIdx.x] = s;
    __syncthreads();
    for (int off = 128; off > 0; off >>= 1) {
        if (threadIdx.x < off) red[threadIdx.x] += red[threadIdx.x + off];
        __syncthreads();
    }
    if (threadIdx.x == 0) bsum[b] = red[0];
}

// scan phase B: one wave; exclusive-scan the 25 tile sums of each graph; write graph totals
__global__ void k_scan_bsum(int* __restrict__ bsum, int* __restrict__ rp) {
    int lane = threadIdx.x;
    for (int g = 0; g < 3; ++g) {
        int v = (lane < SCAN_NB) ? bsum[g * SCAN_NB + lane] : 0;
        int inc = v;
        #pragma unroll
        for (int off = 1; off < 32; off <<= 1) {
            int o = __shfl_up(inc, off, 32);
            if ((lane & 31) >= off) inc += o;
        }
        if (lane < SCAN_NB) bsum[g * SCAN_NB + lane] = inc - v;
        if (lane == SCAN_NB - 1) rp[(size_t)g * (NT + 1) + NT] = inc;
    }
}

// scan phase C: per-tile exclusive scan + tile offset; writes rp
__global__ __launch_bounds__(256) void k_scan_final(const int* __restrict__ deg,
                                                    const int* __restrict__ bsum,
                                                    int* __restrict__ rp) {
    int b = blockIdx.x;
    int g = b / SCAN_NB, t = b % SCAN_NB;
    int tid = threadIdx.x;
    int base = t * SCAN_TILE + tid * 8;
    const int* dg = deg + (size_t)g * NT;
    int* rpg = rp + (size_t)g * (NT + 1);
    int v[8];
    int s = 0;
    if (base + 8 <= NT) {
        int4 a = *reinterpret_cast<const int4*>(dg + base);
        int4 c = *reinterpret_cast<const int4*>(dg + base + 4);
        v[0] = a.x; v[1] = a.y; v[2] = a.z; v[3] = a.w;
        v[4] = c.x; v[5] = c.y; v[6] = c.z; v[7] = c.w;
        s = v[0] + v[1] + v[2] + v[3] + v[4] + v[5] + v[6] + v[7];
    } else {
        #pragma unroll
        for (int i = 0; i < 8; ++i) {
            v[i] = (base + i < NT) ? dg[base + i] : 0;
            s += v[i];
        }
    }
    __shared__ int sums[256];
    sums[tid] = s;
    __syncthreads();
    for (int off = 1; off < 256; off <<= 1) {
        int x = (tid >= off) ? sums[tid - off] : 0;
        __syncthreads();
        sums[tid] += x;
        __syncthreads();
    }
    int run = bsum[b] + (tid ? sums[tid - 1] : 0);
    #pragma unroll
    for (int i = 0; i < 8; ++i) {
        int idx = base + i;
        if (idx < NT) { rpg[idx] = run; run += v[i]; }
    }
}

// bucket pass: only {src, edge-id} (8B) per slot; no atomics (slot = rp[d] + rank[e])
__global__ void k_permute(const int* __restrict__ dt, const int* __restrict__ vt,
                          const int* __restrict__ tt, const int* __restrict__ rank,
                          const int* __restrict__ rp, int2* __restrict__ p1,
                          int2* __restrict__ p2, int2* __restrict__ p3) {
    int e = blockIdx.x * blockDim.x + threadIdx.x;
    if (e < EDT) {
        int d = dt[EDT + e];
        p1[rp[d] + rank[e]] = make_int2(dt[e], e);
    } else if (e < EDT + EVT) {
        int ee = e - EDT;
        int d = vt[EVT + ee];
        p2[rp[(NT + 1) + d] + rank[e]] = make_int2(vt[ee], ee);
    } else if (e < EDT + EVT + ETT) {
        int ee = e - EDT - EVT;
        int d = tt[ETT + ee];
        p3[rp[2 * (NT + 1) + d] + rank[e]] = make_int2(tt[ee], ee);
    }
}

// conv1 gather: bf16 message table (5.1 MB, L2-friendly), head-per-lane 8B loads,
// attention recomputed in fp32 from as1/ad1/ea tables. 32 lanes/dst, unroll x4.
__global__ __launch_bounds__(256) void k_gather_c1(const int* __restrict__ rp,
                                                   const int2* __restrict__ perm,
                                                   const float* __restrict__ as_,
                                                   const float* __restrict__ ad_,
                                                   const float* __restrict__ P,
                                                   const float* __restrict__ ea,
                                                   const unsigned short* __restrict__ hsb,
                                                   const float* __restrict__ bias,
                                                   float* __restrict__ tasks) {
    int tid = threadIdx.x;
    int d = blockIdx.x * 8 + (tid >> 5);
    int lane = tid & 31;
    int h = lane >> 3;
    int c0 = (lane & 7) * 4;
    float Pk[8];
    #pragma unroll
    for (int k = 0; k < 8; ++k) Pk[k] = P[k * 4 + h];
    float base = ad_[d * 4 + h];
    int i0 = rp[d], i1 = rp[d + 1];
    float a0 = 0.f, a1 = 0.f, a2 = 0.f, a3 = 0.f, den = 0.f;
    int i = i0;
    for (; i + 4 <= i1; i += 4) {
        int2 p0 = perm[i], p1 = perm[i + 1], p2 = perm[i + 2], p3 = perm[i + 3];
        float4 ea0 = *reinterpret_cast<const float4*>(&ea[(size_t)p0.y * 8]);
        float4 eb0 = *reinterpret_cast<const float4*>(&ea[(size_t)p0.y * 8 + 4]);
        float4 ea1 = *reinterpret_cast<const float4*>(&ea[(size_t)p1.y * 8]);
        float4 eb1 = *reinterpret_cast<const float4*>(&ea[(size_t)p1.y * 8 + 4]);
        float4 ea2 = *reinterpret_cast<const float4*>(&ea[(size_t)p2.y * 8]);
        float4 eb2 = *reinterpret_cast<const float4*>(&ea[(size_t)p2.y * 8 + 4]);
        float4 ea3 = *reinterpret_cast<const float4*>(&ea[(size_t)p3.y * 8]);
        float4 eb3 = *reinterpret_cast<const float4*>(&ea[(size_t)p3.y * 8 + 4]);
        float l0 = base + as_[p0.x * 4 + h];
        float l1 = base + as_[p1.x * 4 + h];
        float l2 = base + as_[p2.x * 4 + h];
        float l3 = base + as_[p3.x * 4 + h];
        ushort4 m0 = *reinterpret_cast<const ushort4*>(&hsb[(size_t)p0.x * 128 + h * 32 + c0]);
        ushort4 m1 = *reinterpret_cast<const ushort4*>(&hsb[(size_t)p1.x * 128 + h * 32 + c0]);
        ushort4 m2 = *reinterpret_cast<const ushort4*>(&hsb[(size_t)p2.x * 128 + h * 32 + c0]);
        ushort4 m3 = *reinterpret_cast<const ushort4*>(&hsb[(size_t)p3.x * 128 + h * 32 + c0]);
        l0 += ea0.x * Pk[0] + ea0.y * Pk[1] + ea0.z * Pk[2] + ea0.w * Pk[3]
            + eb0.x * Pk[4] + eb0.y * Pk[5] + eb0.z * Pk[6] + eb0.w * Pk[7];
        l1 += ea1.x * Pk[0] + ea1.y * Pk[1] + ea1.z * Pk[2] + ea1.w * Pk[3]
            + eb1.x * Pk[4] + eb1.y * Pk[5] + eb1.z * Pk[6] + eb1.w * Pk[7];
        l2 += ea2.x * Pk[0] + ea2.y * Pk[1] + ea2.z * Pk[2] + ea2.w * Pk[3]
            + eb2.x * Pk[4] + eb2.y * Pk[5] + eb2.z * Pk[6] + eb2.w * Pk[7];
        l3 += ea3.x * Pk[0] + ea3.y * Pk[1] + ea3.z * Pk[2] + ea3.w * Pk[3]
            + eb3.x * Pk[4] + eb3.y * Pk[5] + eb3.z * Pk[6] + eb3.w * Pk[7];
        float w0 = expf(lrelu(l0)), w1 = expf(lrelu(l1));
        float w2 = expf(lrelu(l2)), w3 = expf(lrelu(l3));
        a0 += w0 * bf2f(m0.x) + w1 * bf2f(m1.x) + w2 * bf2f(m2.x) + w3 * bf2f(m3.x);
        a1 += w0 * bf2f(m0.y) + w1 * bf2f(m1.y) + w2 * bf2f(m2.y) + w3 * bf2f(m3.y);
        a2 += w0 * bf2f(m0.z) + w1 * bf2f(m1.z) + w2 * bf2f(m2.z) + w3 * bf2f(m3.z);
        a3 += w0 * bf2f(m0.w) + w1 * bf2f(m1.w) + w2 * bf2f(m2.w) + w3 * bf2f(m3.w);
        den += w0 + w1 + w2 + w3;
    }
    for (; i < i1; ++i) {
        int2 p = perm[i];
        float4 EA = *reinterpret_cast<const float4*>(&ea[(size_t)p.y * 8]);
        float4 EB = *reinterpret_cast<const float4*>(&ea[(size_t)p.y * 8 + 4]);
        ushort4 m = *reinterpret_cast<const ushort4*>(&hsb[(size_t)p.x * 128 + h * 32 + c0]);
        float l = base + as_[p.x * 4 + h]
                + EA.x * Pk[0] + EA.y * Pk[1] + EA.z * Pk[2] + EA.w * Pk[3]
                + EB.x * Pk[4] + EB.y * Pk[5] + EB.z * Pk[6] + EB.w * Pk[7];
        float w = expf(lrelu(l));
        a0 += w * bf2f(m.x); a1 += w * bf2f(m.y);
        a2 += w * bf2f(m.z); a3 += w * bf2f(m.w);
        den += w;
    }
    int j0 = h * 32 + c0;
    float4 b4 = *reinterpret_cast<const float4*>(&bias[j0]);
    float r = 1.f / (den + 1e-16f);
    float4 o = make_float4(fmaxf(a0 * r + b4.x, 0.f), fmaxf(a1 * r + b4.y, 0.f),
                           fmaxf(a2 * r + b4.z, 0.f), fmaxf(a3 * r + b4.w, 0.f));
    *reinterpret_cast<float4*>(&tasks[(size_t)d * 256 + j0]) = o;
}

template<int KE>
__device__ __forceinline__ void load_ea(const float* __restrict__ ea, int e, float* v) {
    if (KE == 8) {
        float4 a = *reinterpret_cast<const float4*>(ea + (size_t)e * 8);
        float4 b = *reinterpret_cast<const float4*>(ea + (size_t)e * 8 + 4);
        v[0] = a.x; v[1] = a.y; v[2] = a.z; v[3] = a.w;
        v[4] = b.x; v[5] = b.y; v[6] = b.z; v[7] = b.w;
    } else {
        float2 a = *reinterpret_cast<const float2*>(ea + (size_t)e * 6);
        float2 b = *reinterpret_cast<const float2*>(ea + (size_t)e * 6 + 2);
        float2 c = *reinterpret_cast<const float2*>(ea + (size_t)e * 6 + 4);
        v[0] = a.x; v[1] = a.y; v[2] = b.x; v[3] = b.y; v[4] = c.x; v[5] = c.y;
    }
}

// conv2 gather (message table = 4 rows, cache-resident): recompute attention, unroll x4
template<int KE>
__global__ __launch_bounds__(256) void k_gather12(const int* __restrict__ rp,
                                                  const int2* __restrict__ perm,
                                                  const float* __restrict__ as_,
                                                  const float* __restrict__ ad_,
                                                  const float* __restrict__ P,
                                                  const float* __restrict__ ea,
                                                  const float* __restrict__ hs,
                                                  const float* __restrict__ bias,
                                                  float* __restrict__ tasks, int cbase) {
    int tid = threadIdx.x;
    int d = blockIdx.x * 8 + (tid >> 5);
    int lane = tid & 31;
    int h = lane >> 3;
    float Pk[KE];
    #pragma unroll
    for (int k = 0; k < KE; ++k) Pk[k] = P[k * 4 + h];
    float base = ad_[d * 4 + h];
    int i0 = rp[d], i1 = rp[d + 1];
    float ax = 0.f, ay = 0.f, az = 0.f, aw = 0.f, den = 0.f;
    int i = i0;
    for (; i + 4 <= i1; i += 4) {
        int2 p0 = perm[i], p1 = perm[i + 1], p2 = perm[i + 2], p3 = perm[i + 3];
        float e0[KE], e1[KE], e2[KE], e3[KE];
        load_ea<KE>(ea, p0.y, e0); load_ea<KE>(ea, p1.y, e1);
        load_ea<KE>(ea, p2.y, e2); load_ea<KE>(ea, p3.y, e3);
        float l0 = base + as_[p0.x * 4 + h];
        float l1 = base + as_[p1.x * 4 + h];
        float l2 = base + as_[p2.x * 4 + h];
        float l3 = base + as_[p3.x * 4 + h];
        float4 v0 = *reinterpret_cast<const float4*>(&hs[(size_t)p0.x * 128 + lane * 4]);
        float4 v1 = *reinterpret_cast<const float4*>(&hs[(size_t)p1.x * 128 + lane * 4]);
        float4 v2 = *reinterpret_cast<const float4*>(&hs[(size_t)p2.x * 128 + lane * 4]);
        float4 v3 = *reinterpret_cast<const float4*>(&hs[(size_t)p3.x * 128 + lane * 4]);
        #pragma unroll
        for (int k = 0; k < KE; ++k) {
            l0 += e0[k] * Pk[k]; l1 += e1[k] * Pk[k];
            l2 += e2[k] * Pk[k]; l3 += e3[k] * Pk[k];
        }
        float w0 = expf(lrelu(l0)), w1 = expf(lrelu(l1));
        float w2 = expf(lrelu(l2)), w3 = expf(lrelu(l3));
        ax += v0.x * w0 + v1.x * w1 + v2.x * w2 + v3.x * w3;
        ay += v0.y * w0 + v1.y * w1 + v2.y * w2 + v3.y * w3;
        az += v0.z * w0 + v1.z * w1 + v2.z * w2 + v3.z * w3;
        aw += v0.w * w0 + v1.w * w1 + v2.w * w2 + v3.w * w3;
        den += w0 + w1 + w2 + w3;
    }
    for (; i < i1; ++i) {
        int2 p = perm[i];
        float ev[KE];
        load_ea<KE>(ea, p.y, ev);
        float l = base + as_[p.x * 4 + h];
        #pragma unroll
        for (int k = 0; k < KE; ++k) l += ev[k] * Pk[k];
        float w = expf(lrelu(l));
        float4 v = *reinterpret_cast<const float4*>(&hs[(size_t)p.x * 128 + lane * 4]);
        ax += v.x * w; ay += v.y * w; az += v.z * w; aw += v.w * w;
        den += w;
    }
    float4 b4 = *reinterpret_cast<const float4*>(&bias[lane * 4]);
    float r = 1.f / (den + 1e-16f);
    float4 o = make_float4(fmaxf(ax * r + b4.x, 0.f), fmaxf(ay * r + b4.y, 0.f),
                           fmaxf(az * r + b4.z, 0.f), fmaxf(aw * r + b4.w, 0.f));
    *reinterpret_cast<float4*>(&tasks[(size_t)d * 256 + cbase + lane * 4]) = o;
}

// conv3 gather: bf16 messages, head-per-lane (h=lane>>3, channels 4*(lane&7)..+3),
// per-head softmax + self-loop; head-mean via shfl_xor; +b3, relu fused.
__global__ __launch_bounds__(256) void k_gather_c3(const int* __restrict__ rp,
                                                   const int2* __restrict__ perm,
                                                   const float* __restrict__ as3,
                                                   const float* __restrict__ ad3,
                                                   const float* __restrict__ P3,
                                                   const float* __restrict__ ea,
                                                   const unsigned short* __restrict__ hsb,
                                                   const float* __restrict__ b3,
                                                   float* __restrict__ out) {
    int tid = threadIdx.x;
    int d = blockIdx.x * 8 + (tid >> 5);
    int lane = tid & 31;
    int h = lane >> 3;
    int c0 = (lane & 7) * 4;
    float Pk[4];
    #pragma unroll
    for (int k = 0; k < 4; ++k) Pk[k] = P3[k * 4 + h];
    float adv = ad3[d * 4 + h];
    int i0 = rp[d], i1 = rp[d + 1];
    float a0 = 0.f, a1 = 0.f, a2 = 0.f, a3 = 0.f, den = 0.f, aes = 0.f;
    int i = i0;
    for (; i + 4 <= i1; i += 4) {
        int2 p0 = perm[i], p1 = perm[i + 1], p2 = perm[i + 2], p3 = perm[i + 3];
        float s0 = as3[(size_t)p0.x * 4 + h], s1 = as3[(size_t)p1.x * 4 + h];
        float s2 = as3[(size_t)p2.x * 4 + h], s3 = as3[(size_t)p3.x * 4 + h];
        float4 q0 = *reinterpret_cast<const float4*>(&ea[(size_t)p0.y * 4]);
        float4 q1 = *reinterpret_cast<const float4*>(&ea[(size_t)p1.y * 4]);
        float4 q2 = *reinterpret_cast<const float4*>(&ea[(size_t)p2.y * 4]);
        float4 q3 = *reinterpret_cast<const float4*>(&ea[(size_t)p3.y * 4]);
        ushort4 m0 = *reinterpret_cast<const ushort4*>(&hsb[(size_t)p0.x * 128 + h * 32 + c0]);
        ushort4 m1 = *reinterpret_cast<const ushort4*>(&hsb[(size_t)p1.x * 128 + h * 32 + c0]);
        ushort4 m2 = *reinterpret_cast<const ushort4*>(&hsb[(size_t)p2.x * 128 + h * 32 + c0]);
        ushort4 m3 = *reinterpret_cast<const ushort4*>(&hsb[(size_t)p3.x * 128 + h * 32 + c0]);
        float ae0 = q0.x * Pk[0] + q0.y * Pk[1] + q0.z * Pk[2] + q0.w * Pk[3];
        float ae1 = q1.x * Pk[0] + q1.y * Pk[1] + q1.z * Pk[2] + q1.w * Pk[3];
        float ae2 = q2.x * Pk[0] + q2.y * Pk[1] + q2.z * Pk[2] + q2.w * Pk[3];
        float ae3 = q3.x * Pk[0] + q3.y * Pk[1] + q3.z * Pk[2] + q3.w * Pk[3];
        float w0 = expf(lrelu(s0 + adv + ae0));
        float w1 = expf(lrelu(s1 + adv + ae1));
        float w2 = expf(lrelu(s2 + adv + ae2));
        float w3 = expf(lrelu(s3 + adv + ae3));
        a0 += w0 * bf2f(m0.x) + w1 * bf2f(m1.x) + w2 * bf2f(m2.x) + w3 * bf2f(m3.x);
        a1 += w0 * bf2f(m0.y) + w1 * bf2f(m1.y) + w2 * bf2f(m2.y) + w3 * bf2f(m3.y);
        a2 += w0 * bf2f(m0.z) + w1 * bf2f(m1.z) + w2 * bf2f(m2.z) + w3 * bf2f(m3.z);
        a3 += w0 * bf2f(m0.w) + w1 * bf2f(m1.w) + w2 * bf2f(m2.w) + w3 * bf2f(m3.w);
        den += w0 + w1 + w2 + w3;
        aes += ae0 + ae1 + ae2 + ae3;
    }
    for (; i < i1; ++i) {
        int2 p = perm[i];
        float s = as3[(size_t)p.x * 4 + h];
        float4 q = *reinterpret_cast<const float4*>(&ea[(size_t)p.y * 4]);
        ushort4 m = *reinterpret_cast<const ushort4*>(&hsb[(size_t)p.x * 128 + h * 32 + c0]);
        float ae = q.x * Pk[0] + q.y * Pk[1] + q.z * Pk[2] + q.w * Pk[3];
        float w = expf(lrelu(s + adv + ae));
        a0 += w * bf2f(m.x); a1 += w * bf2f(m.y);
        a2 += w * bf2f(m.z); a3 += w * bf2f(m.w);
        den += w; aes += ae;
    }
    // self loop (mean edge-attr logit), per head
    float cnt = (float)(i1 - i0);
    float mloop = aes / fmaxf(cnt, 1.f);
    float exl = expf(lrelu(as3[(size_t)d * 4 + h] + adv + mloop));
    ushort4 md = *reinterpret_cast<const ushort4*>(&hsb[(size_t)d * 128 + h * 32 + c0]);
    float rden = 1.f / (den + exl + 1e-16f);
    float p0 = (a0 + exl * bf2f(md.x)) * rden;
    float p1 = (a1 + exl * bf2f(md.y)) * rden;
    float p2 = (a2 + exl * bf2f(md.z)) * rden;
    float p3 = (a3 + exl * bf2f(md.w)) * rden;
    // head-mean across lanes {l, l^8, l^16, l^24}
    p0 += __shfl_xor(p0, 8, 32); p0 += __shfl_xor(p0, 16, 32);
    p1 += __shfl_xor(p1, 8, 32); p1 += __shfl_xor(p1, 16, 32);
    p2 += __shfl_xor(p2, 8, 32); p2 += __shfl_xor(p2, 16, 32);
    p3 += __shfl_xor(p3, 8, 32); p3 += __shfl_xor(p3, 16, 32);
    if ((lane >> 3) == 0) {
        float4 o;
        o.x = fmaxf(0.25f * p0 + b3[c0 + 0], 0.f);
        o.y = fmaxf(0.25f * p1 + b3[c0 + 1], 0.f);
        o.z = fmaxf(0.25f * p2 + b3[c0 + 2], 0.f);
        o.w = fmaxf(0.25f * p3 + b3[c0 + 3], 0.f);
        *reinterpret_cast<float4*>(&out[(size_t)d * 32 + c0]) = o;
    }
}

// hs3 = tasks[50000,256] @ W3[256,128] via bf16 split MFMA (Ah*Bh + Ah*Bl + Al*Bh)
__global__ __launch_bounds__(256, 2) void k_gemm_mfma(const float* __restrict__ T,
                                                      const unsigned short* __restrict__ w3hT,
                                                      const unsigned short* __restrict__ w3lT,
                                                      float* __restrict__ outp) {
    __shared__ uint4 sB[2][2048];      // [hi/lo][128 cols x 16 chunks], 64 KiB
    int tid = threadIdx.x;
    int lane = tid & 63;
    int wid = tid >> 6;
    int arow = lane & 15;
    int kgrp = lane >> 4;
    int s0 = blockIdx.x * 8 + wid * 2;
    int ss0 = s0 < 3125 ? s0 : 3124;
    int ss1 = (s0 + 1) < 3125 ? (s0 + 1) : 3124;
    const uint4* w3h4 = reinterpret_cast<const uint4*>(w3hT);
    const uint4* w3l4 = reinterpret_cast<const uint4*>(w3lT);

    v4f acc[2][8];
    #pragma unroll
    for (int sp = 0; sp < 2; ++sp)
        #pragma unroll
        for (int nt = 0; nt < 8; ++nt) acc[sp][nt] = (v4f)0.f;

    #pragma unroll
    for (int kt = 0; kt < 2; ++kt) {
        __syncthreads();
        float4 a0[8], a1[8];
        const float* Ta0 = T + (size_t)(ss0 * 16 + arow) * 256 + kt * 128 + kgrp * 8;
        const float* Ta1 = T + (size_t)(ss1 * 16 + arow) * 256 + kt * 128 + kgrp * 8;
        #pragma unroll
        for (int kc = 0; kc < 4; ++kc) {
            a0[kc * 2]     = *reinterpret_cast<const float4*>(Ta0 + kc * 32);
            a0[kc * 2 + 1] = *reinterpret_cast<const float4*>(Ta0 + kc * 32 + 4);
            a1[kc * 2]     = *reinterpret_cast<const float4*>(Ta1 + kc * 32);
            a1[kc * 2 + 1] = *reinterpret_cast<const float4*>(Ta1 + kc * 32 + 4);
        }
        #pragma unroll
        for (int it = 0; it < 8; ++it) {
            int c = it * 256 + tid;
            int n = c >> 4, ch = c & 15;
            int gi = n * 32 + kt * 16 + ch;
            int li = n * 16 + (ch ^ (n & 7));
            sB[0][li] = w3h4[gi];
            sB[1][li] = w3l4[gi];
        }
        __syncthreads();
        #pragma unroll
        for (int kc = 0; kc < 4; ++kc) {
            v8s ah0, al0, ah1, al1;
            cvt_split(a0[kc * 2], a0[kc * 2 + 1], ah0, al0);
            cvt_split(a1[kc * 2], a1[kc * 2 + 1], ah1, al1);
            #pragma unroll
            for (int nt = 0; nt < 8; ++nt) {
                int col = nt * 16 + arow;
                int ch = kc * 4 + kgrp;
                int li = col * 16 + (ch ^ (col & 7));
                v8s bh = *reinterpret_cast<const v8s*>(&sB[0][li]);
                v8s bl = *reinterpret_cast<const v8s*>(&sB[1][li]);
                acc[0][nt] = __builtin_amdgcn_mfma_f32_16x16x32_bf16(ah0, bh, acc[0][nt], 0, 0, 0);
                acc[0][nt] = __builtin_amdgcn_mfma_f32_16x16x32_bf16(ah0, bl, acc[0][nt], 0, 0, 0);
                acc[0][nt] = __builtin_amdgcn_mfma_f32_16x16x32_bf16(al0, bh, acc[0][nt], 0, 0, 0);
                acc[1][nt] = __builtin_amdgcn_mfma_f32_16x16x32_bf16(ah1, bh, acc[1][nt], 0, 0, 0);
                acc[1][nt] = __builtin_amdgcn_mfma_f32_16x16x32_bf16(ah1, bl, acc[1][nt], 0, 0, 0);
                acc[1][nt] = __builtin_amdgcn_mfma_f32_16x16x32_bf16(al1, bh, acc[1][nt], 0, 0, 0);
            }
        }
    }
    if (s0 < 3125) {
        #pragma unroll
        for (int nt = 0; nt < 8; ++nt)
            #pragma unroll
            for (int i = 0; i < 4; ++i)
                outp[(size_t)(s0 * 16 + kgrp * 4 + i) * 128 + nt * 16 + arow] = acc[0][nt][i];
    }
    if (s0 + 1 < 3125) {
        #pragma unroll
        for (int nt = 0; nt < 8; ++nt)
            #pragma unroll
            for (int i = 0; i < 4; ++i)
                outp[(size_t)((s0 + 1) * 16 + kgrp * 4 + i) * 128 + nt * 16 + arow] = acc[1][nt][i];
    }
}

extern "C" void kernel_launch(void* const* d_in, const int* in_sizes, int n_in,
                              void* d_out, int out_size, void* d_ws, size_t ws_size,
                              hipStream_t stream) {
    const float* x_data  = (const float*)d_in[0];
    const float* x_tasks = (const float*)d_in[1];
    const float* x_dev   = (const float*)d_in[2];
    const int*   ei_dt   = (const int*)d_in[3];
    const float* ea_dt   = (const float*)d_in[4];
    const int*   ei_vt   = (const int*)d_in[5];
    const float* ea_vt   = (const float*)d_in[6];
    const int*   ei_tt   = (const int*)d_in[7];
    const float* ea_tt   = (const float*)d_in[8];
    const float* Ws1 = (const float*)d_in[9];  const float* Wd1 = (const float*)d_in[10];
    const float* We1 = (const float*)d_in[11]; const float* As1 = (const float*)d_in[12];
    const float* Ad1 = (const float*)d_in[13]; const float* Ae1 = (const float*)d_in[14];
    const float* b1  = (const float*)d_in[15];
    const float* Ws2 = (const float*)d_in[16]; const float* Wd2 = (const float*)d_in[17];
    const float* We2 = (const float*)d_in[18]; const float* As2 = (const float*)d_in[19];
    const float* Ad2 = (const float*)d_in[20]; const float* Ae2 = (const float*)d_in[21];
    const float* b2  = (const float*)d_in[22];
    const float* W3  = (const float*)d_in[23]; const float* We3 = (const float*)d_in[24];
    const float* As3 = (const float*)d_in[25]; const float* Ad3 = (const float*)d_in[26];
    const float* Ae3 = (const float*)d_in[27]; const float* b3  = (const float*)d_in[28];

    if (ws_size < WS_TOTAL * sizeof(float)) return;

    float* w = (float*)d_ws;
    float* tasks = w + OFF_TASKS;
    unsigned short* hsb3 = (unsigned short*)(w + OFF_TASKS);  // aliases tasks (dead after gemm)
    float* hs    = w + OFF_HS;                                // hs3
    int*   rank  = (int*)(w + OFF_RANK);
    unsigned short* hsb1 = (unsigned short*)(w + OFF_RANK);   // aliases rank (dead after permute)
    int2*  perm1 = (int2*)(w + OFF_PERM1);
    int2*  perm2 = (int2*)(w + OFF_PERM2);
    int2*  perm3 = (int2*)(w + OFF_PERM3);
    int*   deg   = (int*)(w + OFF_DEG);
    int*   rp    = (int*)(w + OFF_RP);
    int*   bsum  = (int*)(w + OFF_BSUM);
    unsigned short* w3hT = (unsigned short*)(w + OFF_W3HT);
    unsigned short* w3lT = (unsigned short*)(w + OFF_W3LT);
    float* as1 = w + OFF_AS1;
    float* ad1 = w + OFF_AD1; float* as3 = w + OFF_AD1;   // as3 aliases ad1
    float* ad2 = w + OFF_AD2; float* ad3 = w + OFF_AD2;   // ad3 aliases ad2
    float* hs2 = w + OFF_HS2; float* as2 = w + OFF_AS2;
    float* Qs1 = w + OFF_QS1; float* Qd1 = w + OFF_QD1; float* P1 = w + OFF_P1;
    float* Qs2 = w + OFF_QS2; float* Qd2 = w + OFF_QD2; float* P2 = w + OFF_P2;
    float* P3  = w + OFF_P3;
    float* out = (float*)d_out;

    dim3 B(256);
    #define GRID(n) dim3((unsigned)(((n) + 255) / 256))

    // CSR prep: zero degrees, histogram(+rank), hierarchical scan, atomic-free permute
    hipMemsetAsync(deg, 0, 3 * NT * sizeof(int), stream);
    k_proj_small<<<1, 320, 0, stream>>>(Ws1, As1, Wd1, Ad1, We1, Ae1,
                                        Ws2, As2, Wd2, Ad2, We2, Ae2, We3, Ae3,
                                        Qs1, Qd1, P1, Qs2, Qd2, P2, P3);
    k_w3split<<<GRID(256 * 128), B, 0, stream>>>(W3, w3hT, w3lT);
    k_hist<<<GRID(EDT + EVT + ETT), B, 0, stream>>>(ei_dt, ei_vt, ei_tt, deg, rank);
    k_scan_part<<<dim3(3 * SCAN_NB), B, 0, stream>>>(deg, bsum);
    k_scan_bsum<<<1, 64, 0, stream>>>(bsum, rp);
    k_scan_final<<<dim3(3 * SCAN_NB), B, 0, stream>>>(deg, bsum, rp);
    k_permute<<<GRID(EDT + EVT + ETT), B, 0, stream>>>(ei_dt, ei_vt, ei_tt, rank, rp,
                                                       perm1, perm2, perm3);

    // conv1 + conv2 inputs (hsb1 written AFTER permute — it aliases rank)
    k_alpha2<<<GRID(NT * 4), B, 0, stream>>>(x_tasks, Qd1, Qd2, ad1, ad2, NT, 16);
    k_linproj_bf<<<GRID(NDAT * 128), B, 0, stream>>>(x_data, Ws1, hsb1, NDAT, 8);
    k_alpha<<<GRID(NDAT * 4), B, 0, stream>>>(x_data, Qs1, as1, NDAT, 8);
    k_linproj<<<GRID(NDEV * 128), B, 0, stream>>>(x_dev, Ws2, hs2, NDEV, 8);
    k_alpha<<<GRID(NDEV * 4), B, 0, stream>>>(x_dev, Qs2, as2, NDEV, 8);
    // gathers (bias+relu fused)
    k_gather_c1<<<dim3(NT / 8), B, 0, stream>>>(rp, perm1, as1, ad1, P1, ea_dt,
                                                hsb1, b1, tasks);
    k_gather12<6><<<dim3(NT / 8), B, 0, stream>>>(rp + (NT + 1), perm2, as2, ad2, P2, ea_vt,
                                                  hs2, b2, tasks, 128);

    // conv3: tasks -> tasks
    k_gemm_mfma<<<dim3(391), dim3(256), 0, stream>>>(tasks, w3hT, w3lT, hs);
    k_alpha_from_h2<<<GRID(NT * 4), B, 0, stream>>>(hs, As3, Ad3, as3, ad3, hsb3, NT);
    k_gather_c3<<<dim3(NT / 8), B, 0, stream>>>(rp + 2 * (NT + 1), perm3, as3, ad3, P3, ea_tt,
                                                hsb3, b3, out);
    #undef GRID
}

// Round 10
// 243.454 us; speedup vs baseline: 1.7426x; 1.2656x over previous
//
#include <hip/hip_runtime.h>
#include <math.h>

static const int NT = 50000, NDAT = 20000, NDEV = 4;
static const int EDT = 800000, EVT = 200000, ETT = 400000;

// scan geometry: 3 graphs x 25 tiles of 2048 (256 thr x 8 elems)
static const int SCAN_TILE = 2048, SCAN_NB = 25;

// fused-input kernel index ranges
static const int IN_A = NDAT * 128;          // linproj_bf (conv1 messages, bf16)
static const int IN_B = IN_A + NDAT * 4;     // as1
static const int IN_C = IN_B + NT * 4;       // ad1/ad2 (fused)
static const int IN_D = IN_C + NDEV * 128;   // hs2 (fp32)
static const int IN_E = IN_D + NDEV * 4;     // as2
static const int IN_F = IN_E + 256 * 128;    // w3 hi/lo split

// ---------------- workspace layout (float offsets), liveness-aliased ----------------
// Region R = [OFF_HS, OFF_HS+6.4M): pre-gemm suballocs (rank/hsb1/wv1), then hs3 (gemm output).
static const size_t OFF_TASKS = 0;                   // 12,800,000  [NT,256] fp32; hsb3 aliases after gemm
static const size_t OFF_HS    = 12800000;            //  6,400,000  region R
static const size_t OFF_RANK  = OFF_HS;              //  1,400,000 ints (dead after permute_w)
static const size_t OFF_HSB1  = OFF_HS + 1400000;    //  1,280,000 floats = 2.56M ushorts (conv1 bf16 msgs)
static const size_t OFF_WV1   = OFF_HS + 2680000;    //  3,200,000 floats (conv1 weights)  [ends 5,880,000]
static const size_t OFF_WV2   = 19200000;            //    800,000 floats (conv2 weights)
static const size_t OFF_ESRC1 = 20000000;            //    800,000 ints
static const size_t OFF_ESRC2 = 20800000;            //    200,000 ints
static const size_t OFF_PERM3 = 21200000;            //    800,000 floats (int2[ETT])
static const size_t OFF_DEG   = 23200000;            //    150,000  3 x NT ints
static const size_t OFF_RP    = 23350000;            //    150,003  3 x (NT+1) ints
static const size_t OFF_AS1   = 23500004;            //     80,000
static const size_t OFF_AD1   = 23580004;            //    200,000  as3 reuses
static const size_t OFF_AD2   = 23780004;            //    200,000  ad3 reuses
static const size_t OFF_HS2   = 23980004;            //        512
static const size_t OFF_AS2   = 23980516;            //         16
static const size_t OFF_QS1   = 23980532;            //         32
static const size_t OFF_QD1   = 23980564;            //         64
static const size_t OFF_P1    = 23980628;            //         32
static const size_t OFF_QS2   = 23980660;            //         32
static const size_t OFF_QD2   = 23980692;            //         64
static const size_t OFF_P2    = 23980756;            //         24
static const size_t OFF_P3    = 23980780;            //         16
static const size_t OFF_BSUM  = 23980796;            //        128 ints (75 used)
static const size_t OFF_W3HT  = 23980924;            //     16,384 (32768 ushorts, [128n][256k])
static const size_t OFF_W3LT  = 23997308;            //     16,384
static const size_t WS_TOTAL  = 24013692;            // floats (~96 MiB)

typedef short v8s __attribute__((ext_vector_type(8)));
typedef float v4f __attribute__((ext_vector_type(4)));

__device__ __forceinline__ float lrelu(float a) { return a > 0.f ? a : 0.2f * a; }
__device__ __forceinline__ unsigned short f2bf(float x) {
    unsigned int u = __float_as_uint(x);
    return (unsigned short)((u + 0x7FFFu + ((u >> 16) & 1u)) >> 16);
}
__device__ __forceinline__ float bf2f(unsigned short h) {
    return __uint_as_float(((unsigned int)h) << 16);
}
__device__ __forceinline__ void cvt_split(const float4& A, const float4& B, v8s& hi, v8s& lo) {
    union { unsigned short u[8]; v8s v; } H, L;
    float f[8] = {A.x, A.y, A.z, A.w, B.x, B.y, B.z, B.w};
    #pragma unroll
    for (int i = 0; i < 8; ++i) {
        unsigned short h = f2bf(f[i]);
        H.u[i] = h;
        L.u[i] = f2bf(f[i] - bf2f(h));
    }
    hi = H.v; lo = L.v;
}

// Q[k][h] = sum_c W[k*128 + h*32 + c] * A[h*32 + c], for all 7 small matrices
__global__ void k_proj_small(const float* Ws1, const float* As1,
                             const float* Wd1, const float* Ad1,
                             const float* We1, const float* Ae1,
                             const float* Ws2, const float* As2,
                             const float* Wd2, const float* Ad2,
                             const float* We2, const float* Ae2,
                             const float* We3, const float* Ae3,
                             float* Qs1, float* Qd1, float* P1,
                             float* Qs2, float* Qd2, float* P2, float* P3) {
    int t = threadIdx.x;
    const float *W, *A; float* O; int u;
    if      (t < 32)  { W = Ws1; A = As1; O = Qs1; u = t; }
    else if (t < 96)  { W = Wd1; A = Ad1; O = Qd1; u = t - 32; }
    else if (t < 128) { W = We1; A = Ae1; O = P1;  u = t - 96; }
    else if (t < 160) { W = Ws2; A = As2; O = Qs2; u = t - 128; }
    else if (t < 224) { W = Wd2; A = Ad2; O = Qd2; u = t - 160; }
    else if (t < 248) { W = We2; A = Ae2; O = P2;  u = t - 224; }
    else if (t < 264) { W = We3; A = Ae3; O = P3;  u = t - 248; }
    else return;
    int k = u >> 2, h = u & 3;
    float acc = 0.f;
    for (int c = 0; c < 32; ++c) acc += W[k * 128 + h * 32 + c] * A[h * 32 + c];
    O[k * 4 + h] = acc;
}

// fused input prep: conv1 bf16 messages + as1 + ad1/ad2 + hs2 + as2 + W3 hi/lo split
__global__ __launch_bounds__(256) void k_inputs(const float* __restrict__ x_data,
                                                const float* __restrict__ Ws1,
                                                unsigned short* __restrict__ hsb1,
                                                const float* __restrict__ Qs1,
                                                float* __restrict__ as1,
                                                const float* __restrict__ x_tasks,
                                                const float* __restrict__ Qd1,
                                                const float* __restrict__ Qd2,
                                                float* __restrict__ ad1, float* __restrict__ ad2,
                                                const float* __restrict__ x_dev,
                                                const float* __restrict__ Ws2,
                                                float* __restrict__ hs2,
                                                const float* __restrict__ Qs2,
                                                float* __restrict__ as2,
                                                const float* __restrict__ W3,
                                                unsigned short* __restrict__ w3hT,
                                                unsigned short* __restrict__ w3lT) {
    int idx = blockIdx.x * blockDim.x + threadIdx.x;
    if (idx < IN_A) {                       // conv1 message table, bf16
        int n = idx >> 7, j = idx & 127;
        float acc = 0.f;
        #pragma unroll
        for (int k = 0; k < 8; ++k) acc += x_data[n * 8 + k] * Ws1[k * 128 + j];
        hsb1[idx] = f2bf(acc);
    } else if (idx < IN_B) {                // as1
        int i = idx - IN_A;
        int n = i >> 2, h = i & 3;
        float acc = 0.f;
        #pragma unroll
        for (int k = 0; k < 8; ++k) acc += x_data[n * 8 + k] * Qs1[k * 4 + h];
        as1[i] = acc;
    } else if (idx < IN_C) {                // ad1, ad2 (one pass over x_tasks)
        int i = idx - IN_B;
        int n = i >> 2, h = i & 3;
        float a = 0.f, b = 0.f;
        #pragma unroll
        for (int k = 0; k < 16; ++k) {
            float v = x_tasks[n * 16 + k];
            a += v * Qd1[k * 4 + h];
            b += v * Qd2[k * 4 + h];
        }
        ad1[i] = a; ad2[i] = b;
    } else if (idx < IN_D) {                // hs2 (fp32)
        int i = idx - IN_C;
        int n = i >> 7, j = i & 127;
        float acc = 0.f;
        #pragma unroll
        for (int k = 0; k < 8; ++k) acc += x_dev[n * 8 + k] * Ws2[k * 128 + j];
        hs2[i] = acc;
    } else if (idx < IN_E) {                // as2
        int i = idx - IN_D;
        int n = i >> 2, h = i & 3;
        float acc = 0.f;
        #pragma unroll
        for (int k = 0; k < 8; ++k) acc += x_dev[n * 8 + k] * Qs2[k * 4 + h];
        as2[i] = acc;
    } else if (idx < IN_F) {                // W3 split, transposed
        int i = idx - IN_E;
        int k = i >> 7, n = i & 127;
        float x = W3[i];
        unsigned short h = f2bf(x);
        w3hT[n * 256 + k] = h;
        w3lT[n * 256 + k] = f2bf(x - bf2f(h));
    }
}

// degree histogram for all 3 graphs; also records each edge's rank within its dst
__global__ void k_hist(const int* __restrict__ dt, const int* __restrict__ vt,
                       const int* __restrict__ tt, int* __restrict__ deg,
                       int* __restrict__ rank) {
    int e = blockIdx.x * blockDim.x + threadIdx.x;
    if (e < EDT) rank[e] = atomicAdd(&deg[dt[EDT + e]], 1);
    else if (e < EDT + EVT) rank[e] = atomicAdd(&deg[NT + vt[EVT + (e - EDT)]], 1);
    else if (e < EDT + EVT + ETT) rank[e] = atomicAdd(&deg[2 * NT + tt[ETT + (e - EDT - EVT)]], 1);
}

// scan phase A: per-tile block reduce -> bsum[75]; coalesced int4 loads
__global__ __launch_bounds__(256) void k_scan_part(const int* __restrict__ deg,
                                                   int* __restrict__ bsum) {
    int b = blockIdx.x;
    int g = b / SCAN_NB, t = b % SCAN_NB;
    int base = t * SCAN_TILE + threadIdx.x * 8;
    const int* dg = deg + (size_t)g * NT;
    int s = 0;
    if (base + 8 <= NT) {
        int4 a = *reinterpret_cast<const int4*>(dg + base);
        int4 c = *reinterpret_cast<const int4*>(dg + base + 4);
        s = a.x + a.y + a.z + a.w + c.x + c.y + c.z + c.w;
    } else {
        for (int i = 0; i < 8; ++i) if (base + i < NT) s += dg[base + i];
    }
    __shared__ int red[256];
    red[threadIdx.x] = s;
    __syncthreads();
    for (int off = 128; off > 0; off >>= 1) {
        if (threadIdx.x < off) red[threadIdx.x] += red[threadIdx.x + off];
        __syncthreads();
    }
    if (threadIdx.x == 0) bsum[b] = red[0];
}

// scan phase B: one wave; exclusive-scan the 25 tile sums of each graph; write graph totals
__global__ void k_scan_bsum(int* __restrict__ bsum, int* __restrict__ rp) {
    int lane = threadIdx.x;
    for (int g = 0; g < 3; ++g) {
        int v = (lane < SCAN_NB) ? bsum[g * SCAN_NB + lane] : 0;
        int inc = v;
        #pragma unroll
        for (int off = 1; off < 32; off <<= 1) {
            int o = __shfl_up(inc, off, 32);
            if ((lane & 31) >= off) inc += o;
        }
        if (lane < SCAN_NB) bsum[g * SCAN_NB + lane] = inc - v;
        if (lane == SCAN_NB - 1) rp[(size_t)g * (NT + 1) + NT] = inc;
    }
}

// scan phase C: per-tile exclusive scan + tile offset; writes rp
__global__ __launch_bounds__(256) void k_scan_final(const int* __restrict__ deg,
                                                    const int* __restrict__ bsum,
                                                    int* __restrict__ rp) {
    int b = blockIdx.x;
    int g = b / SCAN_NB, t = b % SCAN_NB;
    int tid = threadIdx.x;
    int base = t * SCAN_TILE + tid * 8;
    const int* dg = deg + (size_t)g * NT;
    int* rpg = rp + (size_t)g * (NT + 1);
    int v[8];
    int s = 0;
    if (base + 8 <= NT) {
        int4 a = *reinterpret_cast<const int4*>(dg + base);
        int4 c = *reinterpret_cast<const int4*>(dg + base + 4);
        v[0] = a.x; v[1] = a.y; v[2] = a.z; v[3] = a.w;
        v[4] = c.x; v[5] = c.y; v[6] = c.z; v[7] = c.w;
        s = v[0] + v[1] + v[2] + v[3] + v[4] + v[5] + v[6] + v[7];
    } else {
        #pragma unroll
        for (int i = 0; i < 8; ++i) {
            v[i] = (base + i < NT) ? dg[base + i] : 0;
            s += v[i];
        }
    }
    __shared__ int sums[256];
    sums[tid] = s;
    __syncthreads();
    for (int off = 1; off < 256; off <<= 1) {
        int x = (tid >= off) ? sums[tid - off] : 0;
        __syncthreads();
        sums[tid] += x;
        __syncthreads();
    }
    int run = bsum[b] + (tid ? sums[tid - 1] : 0);
    #pragma unroll
    for (int i = 0; i < 8; ++i) {
        int idx = base + i;
        if (idx < NT) { rpg[idx] = run; run += v[i]; }
    }
}

// permute + weight precompute: conv1/conv2 scatter {src, w4=exp(leaky(as+ad+ea@P))};
// conv3 scatters {src, edge-id}. No atomics (slot = rp[d] + rank[e]); ea read coalesced.
__global__ void k_permute_w(const int* __restrict__ dt, const int* __restrict__ vt,
                            const int* __restrict__ tt, const int* __restrict__ rank,
                            const int* __restrict__ rp,
                            const float* __restrict__ as1, const float* __restrict__ ad1,
                            const float* __restrict__ P1, const float* __restrict__ ea1,
                            const float* __restrict__ as2, const float* __restrict__ ad2,
                            const float* __restrict__ P2, const float* __restrict__ ea2,
                            int* __restrict__ esrc1, float* __restrict__ wv1,
                            int* __restrict__ esrc2, float* __restrict__ wv2,
                            int2* __restrict__ perm3) {
    int e = blockIdx.x * blockDim.x + threadIdx.x;
    if (e < EDT) {
        int s = dt[e], d = dt[EDT + e];
        int slot = rp[d] + rank[e];
        esrc1[slot] = s;
        float l[4];
        #pragma unroll
        for (int h = 0; h < 4; ++h) l[h] = as1[s * 4 + h] + ad1[d * 4 + h];
        float4 A = *reinterpret_cast<const float4*>(&ea1[(size_t)e * 8]);
        float4 B = *reinterpret_cast<const float4*>(&ea1[(size_t)e * 8 + 4]);
        float ev[8] = {A.x, A.y, A.z, A.w, B.x, B.y, B.z, B.w};
        #pragma unroll
        for (int k = 0; k < 8; ++k)
            #pragma unroll
            for (int h = 0; h < 4; ++h) l[h] += ev[k] * P1[k * 4 + h];
        float4 w4 = make_float4(expf(lrelu(l[0])), expf(lrelu(l[1])),
                                expf(lrelu(l[2])), expf(lrelu(l[3])));
        *reinterpret_cast<float4*>(&wv1[(size_t)slot * 4]) = w4;
    } else if (e < EDT + EVT) {
        int ee = e - EDT;
        int s = vt[ee], d = vt[EVT + ee];
        int slot = rp[(NT + 1) + d] + rank[e];
        esrc2[slot] = s;
        float l[4];
        #pragma unroll
        for (int h = 0; h < 4; ++h) l[h] = as2[s * 4 + h] + ad2[d * 4 + h];
        float2 a = *reinterpret_cast<const float2*>(&ea2[(size_t)ee * 6]);
        float2 b = *reinterpret_cast<const float2*>(&ea2[(size_t)ee * 6 + 2]);
        float2 c = *reinterpret_cast<const float2*>(&ea2[(size_t)ee * 6 + 4]);
        float ev[6] = {a.x, a.y, b.x, b.y, c.x, c.y};
        #pragma unroll
        for (int k = 0; k < 6; ++k)
            #pragma unroll
            for (int h = 0; h < 4; ++h) l[h] += ev[k] * P2[k * 4 + h];
        float4 w4 = make_float4(expf(lrelu(l[0])), expf(lrelu(l[1])),
                                expf(lrelu(l[2])), expf(lrelu(l[3])));
        *reinterpret_cast<float4*>(&wv2[(size_t)slot * 4]) = w4;
    } else if (e < EDT + EVT + ETT) {
        int ee = e - EDT - EVT;
        int d = tt[ETT + ee];
        perm3[rp[2 * (NT + 1) + d] + rank[e]] = make_int2(tt[ee], ee);
    }
}

// conv1 gather: sequential esrc/wv streams; only the 8B bf16 message load is random.
// 32 lanes/dst (head h=lane>>3, channels 4*(lane&7)..+3), unroll x4, bias+relu fused.
__global__ __launch_bounds__(256) void k_gather_c1(const int* __restrict__ rp,
                                                   const int* __restrict__ esrc,
                                                   const float* __restrict__ wv,
                                                   const unsigned short* __restrict__ hsb,
                                                   const float* __restrict__ bias,
                                                   float* __restrict__ tasks) {
    int tid = threadIdx.x;
    int d = blockIdx.x * 8 + (tid >> 5);
    int lane = tid & 31;
    int h = lane >> 3;
    int c0 = (lane & 7) * 4;
    int i0 = rp[d], i1 = rp[d + 1];
    float a0 = 0.f, a1 = 0.f, a2 = 0.f, a3 = 0.f, den = 0.f;
    int i = i0;
    for (; i + 4 <= i1; i += 4) {
        int s0 = esrc[i], s1 = esrc[i + 1], s2 = esrc[i + 2], s3 = esrc[i + 3];
        float w0 = wv[(size_t)i * 4 + h];
        float w1 = wv[(size_t)(i + 1) * 4 + h];
        float w2 = wv[(size_t)(i + 2) * 4 + h];
        float w3 = wv[(size_t)(i + 3) * 4 + h];
        ushort4 m0 = *reinterpret_cast<const ushort4*>(&hsb[(size_t)s0 * 128 + h * 32 + c0]);
        ushort4 m1 = *reinterpret_cast<const ushort4*>(&hsb[(size_t)s1 * 128 + h * 32 + c0]);
        ushort4 m2 = *reinterpret_cast<const ushort4*>(&hsb[(size_t)s2 * 128 + h * 32 + c0]);
        ushort4 m3 = *reinterpret_cast<const ushort4*>(&hsb[(size_t)s3 * 128 + h * 32 + c0]);
        a0 += w0 * bf2f(m0.x) + w1 * bf2f(m1.x) + w2 * bf2f(m2.x) + w3 * bf2f(m3.x);
        a1 += w0 * bf2f(m0.y) + w1 * bf2f(m1.y) + w2 * bf2f(m2.y) + w3 * bf2f(m3.y);
        a2 += w0 * bf2f(m0.z) + w1 * bf2f(m1.z) + w2 * bf2f(m2.z) + w3 * bf2f(m3.z);
        a3 += w0 * bf2f(m0.w) + w1 * bf2f(m1.w) + w2 * bf2f(m2.w) + w3 * bf2f(m3.w);
        den += w0 + w1 + w2 + w3;
    }
    for (; i < i1; ++i) {
        int s = esrc[i];
        float w = wv[(size_t)i * 4 + h];
        ushort4 m = *reinterpret_cast<const ushort4*>(&hsb[(size_t)s * 128 + h * 32 + c0]);
        a0 += w * bf2f(m.x); a1 += w * bf2f(m.y);
        a2 += w * bf2f(m.z); a3 += w * bf2f(m.w);
        den += w;
    }
    int j0 = h * 32 + c0;
    float4 b4 = *reinterpret_cast<const float4*>(&bias[j0]);
    float r = 1.f / (den + 1e-16f);
    float4 o = make_float4(fmaxf(a0 * r + b4.x, 0.f), fmaxf(a1 * r + b4.y, 0.f),
                           fmaxf(a2 * r + b4.z, 0.f), fmaxf(a3 * r + b4.w, 0.f));
    *reinterpret_cast<float4*>(&tasks[(size_t)d * 256 + j0]) = o;
}

// conv2 gather: sequential esrc/wv; message table 2KB fp32 (cache-resident)
__global__ __launch_bounds__(256) void k_gather_c2(const int* __restrict__ rp,
                                                   const int* __restrict__ esrc,
                                                   const float* __restrict__ wv,
                                                   const float* __restrict__ hs2,
                                                   const float* __restrict__ bias,
                                                   float* __restrict__ tasks) {
    int tid = threadIdx.x;
    int d = blockIdx.x * 8 + (tid >> 5);
    int lane = tid & 31;
    int h = lane >> 3;
    int i0 = rp[d], i1 = rp[d + 1];
    float ax = 0.f, ay = 0.f, az = 0.f, aw = 0.f, den = 0.f;
    int i = i0;
    for (; i + 4 <= i1; i += 4) {
        int s0 = esrc[i], s1 = esrc[i + 1], s2 = esrc[i + 2], s3 = esrc[i + 3];
        float w0 = wv[(size_t)i * 4 + h];
        float w1 = wv[(size_t)(i + 1) * 4 + h];
        float w2 = wv[(size_t)(i + 2) * 4 + h];
        float w3 = wv[(size_t)(i + 3) * 4 + h];
        float4 v0 = *reinterpret_cast<const float4*>(&hs2[s0 * 128 + lane * 4]);
        float4 v1 = *reinterpret_cast<const float4*>(&hs2[s1 * 128 + lane * 4]);
        float4 v2 = *reinterpret_cast<const float4*>(&hs2[s2 * 128 + lane * 4]);
        float4 v3 = *reinterpret_cast<const float4*>(&hs2[s3 * 128 + lane * 4]);
        ax += v0.x * w0 + v1.x * w1 + v2.x * w2 + v3.x * w3;
        ay += v0.y * w0 + v1.y * w1 + v2.y * w2 + v3.y * w3;
        az += v0.z * w0 + v1.z * w1 + v2.z * w2 + v3.z * w3;
        aw += v0.w * w0 + v1.w * w1 + v2.w * w2 + v3.w * w3;
        den += w0 + w1 + w2 + w3;
    }
    for (; i < i1; ++i) {
        int s = esrc[i];
        float w = wv[(size_t)i * 4 + h];
        float4 v = *reinterpret_cast<const float4*>(&hs2[s * 128 + lane * 4]);
        ax += v.x * w; ay += v.y * w; az += v.z * w; aw += v.w * w;
        den += w;
    }
    float4 b4 = *reinterpret_cast<const float4*>(&bias[lane * 4]);
    float r = 1.f / (den + 1e-16f);
    float4 o = make_float4(fmaxf(ax * r + b4.x, 0.f), fmaxf(ay * r + b4.y, 0.f),
                           fmaxf(az * r + b4.z, 0.f), fmaxf(aw * r + b4.w, 0.f));
    *reinterpret_cast<float4*>(&tasks[(size_t)d * 256 + 128 + lane * 4]) = o;
}

// fused: as3/ad3 from one float4-vectorized pass over hs3; also emits bf16 copy hsb
__global__ void k_alpha_from_h2(const float* __restrict__ hs, const float* __restrict__ As,
                                const float* __restrict__ Ad, float* __restrict__ oa,
                                float* __restrict__ ob, unsigned short* __restrict__ hsb,
                                int N) {
    int idx = blockIdx.x * blockDim.x + threadIdx.x;
    if (idx >= N * 4) return;
    int n = idx >> 2, h = idx & 3;
    const float* row = hs + (size_t)n * 128 + h * 32;
    unsigned short* brow = hsb + (size_t)n * 128 + h * 32;
    float a = 0.f, b = 0.f;
    #pragma unroll
    for (int c = 0; c < 32; c += 4) {
        float4 v = *reinterpret_cast<const float4*>(row + c);
        a += v.x * As[h * 32 + c]     + v.y * As[h * 32 + c + 1]
           + v.z * As[h * 32 + c + 2] + v.w * As[h * 32 + c + 3];
        b += v.x * Ad[h * 32 + c]     + v.y * Ad[h * 32 + c + 1]
           + v.z * Ad[h * 32 + c + 2] + v.w * Ad[h * 32 + c + 3];
        ushort4 pk;
        pk.x = f2bf(v.x); pk.y = f2bf(v.y); pk.z = f2bf(v.z); pk.w = f2bf(v.w);
        *reinterpret_cast<ushort4*>(brow + c) = pk;
    }
    oa[idx] = a; ob[idx] = b;
}

// conv3 gather: bf16 messages, head-per-lane; per-head softmax + self-loop (mean edge-attr);
// head-mean via shfl_xor; +b3, relu fused. Writes d_out once.
__global__ __launch_bounds__(256) void k_gather_c3(const int* __restrict__ rp,
                                                   const int2* __restrict__ perm,
                                                   const float* __restrict__ as3,
                                                   const float* __restrict__ ad3,
                                                   const float* __restrict__ P3,
                                                   const float* __restrict__ ea,
                                                   const unsigned short* __restrict__ hsb,
                                                   const float* __restrict__ b3,
                                                   float* __restrict__ out) {
    int tid = threadIdx.x;
    int d = blockIdx.x * 8 + (tid >> 5);
    int lane = tid & 31;
    int h = lane >> 3;
    int c0 = (lane & 7) * 4;
    float Pk[4];
    #pragma unroll
    for (int k = 0; k < 4; ++k) Pk[k] = P3[k * 4 + h];
    float adv = ad3[d * 4 + h];
    int i0 = rp[d], i1 = rp[d + 1];
    float a0 = 0.f, a1 = 0.f, a2 = 0.f, a3 = 0.f, den = 0.f, aes = 0.f;
    int i = i0;
    for (; i + 4 <= i1; i += 4) {
        int2 p0 = perm[i], p1 = perm[i + 1], p2 = perm[i + 2], p3 = perm[i + 3];
        float s0 = as3[(size_t)p0.x * 4 + h], s1 = as3[(size_t)p1.x * 4 + h];
        float s2 = as3[(size_t)p2.x * 4 + h], s3 = as3[(size_t)p3.x * 4 + h];
        float4 q0 = *reinterpret_cast<const float4*>(&ea[(size_t)p0.y * 4]);
        float4 q1 = *reinterpret_cast<const float4*>(&ea[(size_t)p1.y * 4]);
        float4 q2 = *reinterpret_cast<const float4*>(&ea[(size_t)p2.y * 4]);
        float4 q3 = *reinterpret_cast<const float4*>(&ea[(size_t)p3.y * 4]);
        ushort4 m0 = *reinterpret_cast<const ushort4*>(&hsb[(size_t)p0.x * 128 + h * 32 + c0]);
        ushort4 m1 = *reinterpret_cast<const ushort4*>(&hsb[(size_t)p1.x * 128 + h * 32 + c0]);
        ushort4 m2 = *reinterpret_cast<const ushort4*>(&hsb[(size_t)p2.x * 128 + h * 32 + c0]);
        ushort4 m3 = *reinterpret_cast<const ushort4*>(&hsb[(size_t)p3.x * 128 + h * 32 + c0]);
        float ae0 = q0.x * Pk[0] + q0.y * Pk[1] + q0.z * Pk[2] + q0.w * Pk[3];
        float ae1 = q1.x * Pk[0] + q1.y * Pk[1] + q1.z * Pk[2] + q1.w * Pk[3];
        float ae2 = q2.x * Pk[0] + q2.y * Pk[1] + q2.z * Pk[2] + q2.w * Pk[3];
        float ae3 = q3.x * Pk[0] + q3.y * Pk[1] + q3.z * Pk[2] + q3.w * Pk[3];
        float w0 = expf(lrelu(s0 + adv + ae0));
        float w1 = expf(lrelu(s1 + adv + ae1));
        float w2 = expf(lrelu(s2 + adv + ae2));
        float w3 = expf(lrelu(s3 + adv + ae3));
        a0 += w0 * bf2f(m0.x) + w1 * bf2f(m1.x) + w2 * bf2f(m2.x) + w3 * bf2f(m3.x);
        a1 += w0 * bf2f(m0.y) + w1 * bf2f(m1.y) + w2 * bf2f(m2.y) + w3 * bf2f(m3.y);
        a2 += w0 * bf2f(m0.z) + w1 * bf2f(m1.z) + w2 * bf2f(m2.z) + w3 * bf2f(m3.z);
        a3 += w0 * bf2f(m0.w) + w1 * bf2f(m1.w) + w2 * bf2f(m2.w) + w3 * bf2f(m3.w);
        den += w0 + w1 + w2 + w3;
        aes += ae0 + ae1 + ae2 + ae3;
    }
    for (; i < i1; ++i) {
        int2 p = perm[i];
        float s = as3[(size_t)p.x * 4 + h];
        float4 q = *reinterpret_cast<const float4*>(&ea[(size_t)p.y * 4]);
        ushort4 m = *reinterpret_cast<const ushort4*>(&hsb[(size_t)p.x * 128 + h * 32 + c0]);
        float ae = q.x * Pk[0] + q.y * Pk[1] + q.z * Pk[2] + q.w * Pk[3];
        float w = expf(lrelu(s + adv + ae));
        a0 += w * bf2f(m.x); a1 += w * bf2f(m.y);
        a2 += w * bf2f(m.z); a3 += w * bf2f(m.w);
        den += w; aes += ae;
    }
    float cnt = (float)(i1 - i0);
    float mloop = aes / fmaxf(cnt, 1.f);
    float exl = expf(lrelu(as3[(size_t)d * 4 + h] + adv + mloop));
    ushort4 md = *reinterpret_cast<const ushort4*>(&hsb[(size_t)d * 128 + h * 32 + c0]);
    float rden = 1.f / (den + exl + 1e-16f);
    float p0 = (a0 + exl * bf2f(md.x)) * rden;
    float p1 = (a1 + exl * bf2f(md.y)) * rden;
    float p2 = (a2 + exl * bf2f(md.z)) * rden;
    float p3 = (a3 + exl * bf2f(md.w)) * rden;
    p0 += __shfl_xor(p0, 8, 32); p0 += __shfl_xor(p0, 16, 32);
    p1 += __shfl_xor(p1, 8, 32); p1 += __shfl_xor(p1, 16, 32);
    p2 += __shfl_xor(p2, 8, 32); p2 += __shfl_xor(p2, 16, 32);
    p3 += __shfl_xor(p3, 8, 32); p3 += __shfl_xor(p3, 16, 32);
    if ((lane >> 3) == 0) {
        float4 o;
        o.x = fmaxf(0.25f * p0 + b3[c0 + 0], 0.f);
        o.y = fmaxf(0.25f * p1 + b3[c0 + 1], 0.f);
        o.z = fmaxf(0.25f * p2 + b3[c0 + 2], 0.f);
        o.w = fmaxf(0.25f * p3 + b3[c0 + 3], 0.f);
        *reinterpret_cast<float4*>(&out[(size_t)d * 32 + c0]) = o;
    }
}

// hs3 = tasks[50000,256] @ W3[256,128] via bf16 split MFMA (Ah*Bh + Ah*Bl + Al*Bh)
__global__ __launch_bounds__(256, 2) void k_gemm_mfma(const float* __restrict__ T,
                                                      const unsigned short* __restrict__ w3hT,
                                                      const unsigned short* __restrict__ w3lT,
                                                      float* __restrict__ outp) {
    __shared__ uint4 sB[2][2048];      // [hi/lo][128 cols x 16 chunks], 64 KiB
    int tid = threadIdx.x;
    int lane = tid & 63;
    int wid = tid >> 6;
    int arow = lane & 15;
    int kgrp = lane >> 4;
    int s0 = blockIdx.x * 8 + wid * 2;
    int ss0 = s0 < 3125 ? s0 : 3124;
    int ss1 = (s0 + 1) < 3125 ? (s0 + 1) : 3124;
    const uint4* w3h4 = reinterpret_cast<const uint4*>(w3hT);
    const uint4* w3l4 = reinterpret_cast<const uint4*>(w3lT);

    v4f acc[2][8];
    #pragma unroll
    for (int sp = 0; sp < 2; ++sp)
        #pragma unroll
        for (int nt = 0; nt < 8; ++nt) acc[sp][nt] = (v4f)0.f;

    #pragma unroll
    for (int kt = 0; kt < 2; ++kt) {
        __syncthreads();
        float4 a0[8], a1[8];
        const float* Ta0 = T + (size_t)(ss0 * 16 + arow) * 256 + kt * 128 + kgrp * 8;
        const float* Ta1 = T + (size_t)(ss1 * 16 + arow) * 256 + kt * 128 + kgrp * 8;
        #pragma unroll
        for (int kc = 0; kc < 4; ++kc) {
            a0[kc * 2]     = *reinterpret_cast<const float4*>(Ta0 + kc * 32);
            a0[kc * 2 + 1] = *reinterpret_cast<const float4*>(Ta0 + kc * 32 + 4);
            a1[kc * 2]     = *reinterpret_cast<const float4*>(Ta1 + kc * 32);
            a1[kc * 2 + 1] = *reinterpret_cast<const float4*>(Ta1 + kc * 32 + 4);
        }
        #pragma unroll
        for (int it = 0; it < 8; ++it) {
            int c = it * 256 + tid;
            int n = c >> 4, ch = c & 15;
            int gi = n * 32 + kt * 16 + ch;
            int li = n * 16 + (ch ^ (n & 7));
            sB[0][li] = w3h4[gi];
            sB[1][li] = w3l4[gi];
        }
        __syncthreads();
        #pragma unroll
        for (int kc = 0; kc < 4; ++kc) {
            v8s ah0, al0, ah1, al1;
            cvt_split(a0[kc * 2], a0[kc * 2 + 1], ah0, al0);
            cvt_split(a1[kc * 2], a1[kc * 2 + 1], ah1, al1);
            #pragma unroll
            for (int nt = 0; nt < 8; ++nt) {
                int col = nt * 16 + arow;
                int ch = kc * 4 + kgrp;
                int li = col * 16 + (ch ^ (col & 7));
                v8s bh = *reinterpret_cast<const v8s*>(&sB[0][li]);
                v8s bl = *reinterpret_cast<const v8s*>(&sB[1][li]);
                acc[0][nt] = __builtin_amdgcn_mfma_f32_16x16x32_bf16(ah0, bh, acc[0][nt], 0, 0, 0);
                acc[0][nt] = __builtin_amdgcn_mfma_f32_16x16x32_bf16(ah0, bl, acc[0][nt], 0, 0, 0);
                acc[0][nt] = __builtin_amdgcn_mfma_f32_16x16x32_bf16(al0, bh, acc[0][nt], 0, 0, 0);
                acc[1][nt] = __builtin_amdgcn_mfma_f32_16x16x32_bf16(ah1, bh, acc[1][nt], 0, 0, 0);
                acc[1][nt] = __builtin_amdgcn_mfma_f32_16x16x32_bf16(ah1, bl, acc[1][nt], 0, 0, 0);
                acc[1][nt] = __builtin_amdgcn_mfma_f32_16x16x32_bf16(al1, bh, acc[1][nt], 0, 0, 0);
            }
        }
    }
    if (s0 < 3125) {
        #pragma unroll
        for (int nt = 0; nt < 8; ++nt)
            #pragma unroll
            for (int i = 0; i < 4; ++i)
                outp[(size_t)(s0 * 16 + kgrp * 4 + i) * 128 + nt * 16 + arow] = acc[0][nt][i];
    }
    if (s0 + 1 < 3125) {
        #pragma unroll
        for (int nt = 0; nt < 8; ++nt)
            #pragma unroll
            for (int i = 0; i < 4; ++i)
                outp[(size_t)((s0 + 1) * 16 + kgrp * 4 + i) * 128 + nt * 16 + arow] = acc[1][nt][i];
    }
}

extern "C" void kernel_launch(void* const* d_in, const int* in_sizes, int n_in,
                              void* d_out, int out_size, void* d_ws, size_t ws_size,
                              hipStream_t stream) {
    const float* x_data  = (const float*)d_in[0];
    const float* x_tasks = (const float*)d_in[1];
    const float* x_dev   = (const float*)d_in[2];
    const int*   ei_dt   = (const int*)d_in[3];
    const float* ea_dt   = (const float*)d_in[4];
    const int*   ei_vt   = (const int*)d_in[5];
    const float* ea_vt   = (const float*)d_in[6];
    const int*   ei_tt   = (const int*)d_in[7];
    const float* ea_tt   = (const float*)d_in[8];
    const float* Ws1 = (const float*)d_in[9];  const float* Wd1 = (const float*)d_in[10];
    const float* We1 = (const float*)d_in[11]; const float* As1 = (const float*)d_in[12];
    const float* Ad1 = (const float*)d_in[13]; const float* Ae1 = (const float*)d_in[14];
    const float* b1  = (const float*)d_in[15];
    const float* Ws2 = (const float*)d_in[16]; const float* Wd2 = (const float*)d_in[17];
    const float* We2 = (const float*)d_in[18]; const float* As2 = (const float*)d_in[19];
    const float* Ad2 = (const float*)d_in[20]; const float* Ae2 = (const float*)d_in[21];
    const float* b2  = (const float*)d_in[22];
    const float* W3  = (const float*)d_in[23]; const float* We3 = (const float*)d_in[24];
    const float* As3 = (const float*)d_in[25]; const float* Ad3 = (const float*)d_in[26];
    const float* Ae3 = (const float*)d_in[27]; const float* b3  = (const float*)d_in[28];

    if (ws_size < WS_TOTAL * sizeof(float)) return;

    float* w = (float*)d_ws;
    float* tasks = w + OFF_TASKS;
    unsigned short* hsb3 = (unsigned short*)(w + OFF_TASKS);  // aliases tasks (dead after gemm)
    float* hs    = w + OFF_HS;                                // hs3 (written by gemm)
    int*   rank  = (int*)(w + OFF_RANK);
    unsigned short* hsb1 = (unsigned short*)(w + OFF_HSB1);
    float* wv1   = w + OFF_WV1;
    float* wv2   = w + OFF_WV2;
    int*   esrc1 = (int*)(w + OFF_ESRC1);
    int*   esrc2 = (int*)(w + OFF_ESRC2);
    int2*  perm3 = (int2*)(w + OFF_PERM3);
    int*   deg   = (int*)(w + OFF_DEG);
    int*   rp    = (int*)(w + OFF_RP);
    int*   bsum  = (int*)(w + OFF_BSUM);
    unsigned short* w3hT = (unsigned short*)(w + OFF_W3HT);
    unsigned short* w3lT = (unsigned short*)(w + OFF_W3LT);
    float* as1 = w + OFF_AS1;
    float* ad1 = w + OFF_AD1; float* as3 = w + OFF_AD1;   // as3 aliases ad1
    float* ad2 = w + OFF_AD2; float* ad3 = w + OFF_AD2;   // ad3 aliases ad2
    float* hs2 = w + OFF_HS2; float* as2 = w + OFF_AS2;
    float* Qs1 = w + OFF_QS1; float* Qd1 = w + OFF_QD1; float* P1 = w + OFF_P1;
    float* Qs2 = w + OFF_QS2; float* Qd2 = w + OFF_QD2; float* P2 = w + OFF_P2;
    float* P3  = w + OFF_P3;
    float* out = (float*)d_out;

    dim3 B(256);
    #define GRID(n) dim3((unsigned)(((n) + 255) / 256))

    hipMemsetAsync(deg, 0, 3 * NT * sizeof(int), stream);
    k_proj_small<<<1, 320, 0, stream>>>(Ws1, As1, Wd1, Ad1, We1, Ae1,
                                        Ws2, As2, Wd2, Ad2, We2, Ae2, We3, Ae3,
                                        Qs1, Qd1, P1, Qs2, Qd2, P2, P3);
    k_inputs<<<GRID(IN_F), B, 0, stream>>>(x_data, Ws1, hsb1, Qs1, as1,
                                           x_tasks, Qd1, Qd2, ad1, ad2,
                                           x_dev, Ws2, hs2, Qs2, as2,
                                           W3, w3hT, w3lT);
    k_hist<<<GRID(EDT + EVT + ETT), B, 0, stream>>>(ei_dt, ei_vt, ei_tt, deg, rank);
    k_scan_part<<<dim3(3 * SCAN_NB), B, 0, stream>>>(deg, bsum);
    k_scan_bsum<<<1, 64, 0, stream>>>(bsum, rp);
    k_scan_final<<<dim3(3 * SCAN_NB), B, 0, stream>>>(deg, bsum, rp);
    k_permute_w<<<GRID(EDT + EVT + ETT), B, 0, stream>>>(ei_dt, ei_vt, ei_tt, rank, rp,
                                                         as1, ad1, P1, ea_dt,
                                                         as2, ad2, P2, ea_vt,
                                                         esrc1, wv1, esrc2, wv2, perm3);
    // gathers (bias+relu fused; weights precomputed in dst-sorted order)
    k_gather_c1<<<dim3(NT / 8), B, 0, stream>>>(rp, esrc1, wv1, hsb1, b1, tasks);
    k_gather_c2<<<dim3(NT / 8), B, 0, stream>>>(rp + (NT + 1), esrc2, wv2, hs2, b2, tasks);

    // conv3: tasks -> tasks
    k_gemm_mfma<<<dim3(391), dim3(256), 0, stream>>>(tasks, w3hT, w3lT, hs);
    k_alpha_from_h2<<<GRID(NT * 4), B, 0, stream>>>(hs, As3, Ad3, as3, ad3, hsb3, NT);
    k_gather_c3<<<dim3(NT / 8), B, 0, stream>>>(rp + 2 * (NT + 1), perm3, as3, ad3, P3, ea_tt,
                                                hsb3, b3, out);
    #undef GRID
}

// Round 11
// 232.476 us; speedup vs baseline: 1.8249x; 1.0472x over previous
//
#include <hip/hip_runtime.h>
#include <math.h>

static const int NT = 50000, NDAT = 20000, NDEV = 4;
static const int EDT = 800000, EVT = 200000, ETT = 400000;

// scan geometry: 3 graphs x 25 tiles of 2048 (256 thr x 8 elems)
static const int SCAN_TILE = 2048, SCAN_NB = 25;

// fused-input kernel index ranges
static const int IN_A = NDAT * 128;          // linproj_bf (conv1 messages, bf16)
static const int IN_B = IN_A + NDAT * 4;     // as1
static const int IN_C = IN_B + NT * 4;       // ad1/ad2 (fused)
static const int IN_D = IN_C + NDEV * 128;   // hs2 (fp32)
static const int IN_E = IN_D + NDEV * 4;     // as2
static const int IN_F = IN_E + 256 * 128;    // w3 hi/lo split

// ---------------- workspace layout (float offsets), liveness-aliased ----------------
// Region R = [OFF_HS, OFF_HS+6.4M): pre-gemm suballocs (rank/hsb1/rec1), then hs3 (gemm output).
static const size_t OFF_TASKS = 0;                   // 12,800,000  [NT,256] fp32; hsb3 aliases after gemm
static const size_t OFF_HS    = 12800000;            //  6,400,000  region R
static const size_t OFF_RANK  = OFF_HS;              //  1,400,000 ints (dead after permute_w)
static const size_t OFF_HSB1  = OFF_HS + 1400000;    //  1,280,000 floats = 2.56M ushorts (conv1 bf16 msgs)
static const size_t OFF_REC1  = OFF_HS + 2680000;    //  3,200,000 floats (800k x 16B records) [ends 5,880,000]
static const size_t OFF_REC2  = 19200000;            //    800,000 floats (200k x 16B records)
static const size_t OFF_REC3  = 20000000;            //  1,600,000 floats (400k x 16B records)
static const size_t OFF_DEG   = 23200000;            //    150,000  3 x NT ints
static const size_t OFF_RP    = 23350000;            //    150,003  3 x (NT+1) ints
static const size_t OFF_AS1   = 23500004;            //     80,000
static const size_t OFF_AD1   = 23580004;            //    200,000  as3 reuses
static const size_t OFF_AD2   = 23780004;            //    200,000  ad3 reuses
static const size_t OFF_HS2   = 23980004;            //        512
static const size_t OFF_AS2   = 23980516;            //         16
static const size_t OFF_QS1   = 23980532;            //         32
static const size_t OFF_QD1   = 23980564;            //         64
static const size_t OFF_P1    = 23980628;            //         32
static const size_t OFF_QS2   = 23980660;            //         32
static const size_t OFF_QD2   = 23980692;            //         64
static const size_t OFF_P2    = 23980756;            //         24
static const size_t OFF_P3    = 23980780;            //         16
static const size_t OFF_BSUM  = 23980796;            //        128 ints (75 used)
static const size_t OFF_W3HT  = 23980924;            //     16,384 (32768 ushorts, [128n][256k])
static const size_t OFF_W3LT  = 23997308;            //     16,384
static const size_t WS_TOTAL  = 24013692;            // floats (~96 MiB)

typedef short v8s __attribute__((ext_vector_type(8)));
typedef float v4f __attribute__((ext_vector_type(4)));

__device__ __forceinline__ float lrelu(float a) { return a > 0.f ? a : 0.2f * a; }
__device__ __forceinline__ unsigned short f2bf(float x) {
    unsigned int u = __float_as_uint(x);
    return (unsigned short)((u + 0x7FFFu + ((u >> 16) & 1u)) >> 16);
}
__device__ __forceinline__ float bf2f(unsigned short h) {
    return __uint_as_float(((unsigned int)h) << 16);
}
// select the h-th bf16 from the pair of packed words (w0|w1<<16, w2|w3<<16)
__device__ __forceinline__ float bfsel(unsigned int lo01, unsigned int lo23, int h) {
    unsigned int word = (h < 2) ? lo01 : lo23;
    return bf2f((unsigned short)((h & 1) ? (word >> 16) : (word & 0xFFFFu)));
}
__device__ __forceinline__ void cvt_split(const float4& A, const float4& B, v8s& hi, v8s& lo) {
    union { unsigned short u[8]; v8s v; } H, L;
    float f[8] = {A.x, A.y, A.z, A.w, B.x, B.y, B.z, B.w};
    #pragma unroll
    for (int i = 0; i < 8; ++i) {
        unsigned short h = f2bf(f[i]);
        H.u[i] = h;
        L.u[i] = f2bf(f[i] - bf2f(h));
    }
    hi = H.v; lo = L.v;
}

// Q[k][h] = sum_c W[k*128 + h*32 + c] * A[h*32 + c], for all 7 small matrices
__global__ void k_proj_small(const float* Ws1, const float* As1,
                             const float* Wd1, const float* Ad1,
                             const float* We1, const float* Ae1,
                             const float* Ws2, const float* As2,
                             const float* Wd2, const float* Ad2,
                             const float* We2, const float* Ae2,
                             const float* We3, const float* Ae3,
                             float* Qs1, float* Qd1, float* P1,
                             float* Qs2, float* Qd2, float* P2, float* P3) {
    int t = threadIdx.x;
    const float *W, *A; float* O; int u;
    if      (t < 32)  { W = Ws1; A = As1; O = Qs1; u = t; }
    else if (t < 96)  { W = Wd1; A = Ad1; O = Qd1; u = t - 32; }
    else if (t < 128) { W = We1; A = Ae1; O = P1;  u = t - 96; }
    else if (t < 160) { W = Ws2; A = As2; O = Qs2; u = t - 128; }
    else if (t < 224) { W = Wd2; A = Ad2; O = Qd2; u = t - 160; }
    else if (t < 248) { W = We2; A = Ae2; O = P2;  u = t - 224; }
    else if (t < 264) { W = We3; A = Ae3; O = P3;  u = t - 248; }
    else return;
    int k = u >> 2, h = u & 3;
    float acc = 0.f;
    for (int c = 0; c < 32; ++c) acc += W[k * 128 + h * 32 + c] * A[h * 32 + c];
    O[k * 4 + h] = acc;
}

// fused input prep: conv1 bf16 messages + as1 + ad1/ad2 + hs2 + as2 + W3 hi/lo split
__global__ __launch_bounds__(256) void k_inputs(const float* __restrict__ x_data,
                                                const float* __restrict__ Ws1,
                                                unsigned short* __restrict__ hsb1,
                                                const float* __restrict__ Qs1,
                                                float* __restrict__ as1,
                                                const float* __restrict__ x_tasks,
                                                const float* __restrict__ Qd1,
                                                const float* __restrict__ Qd2,
                                                float* __restrict__ ad1, float* __restrict__ ad2,
                                                const float* __restrict__ x_dev,
                                                const float* __restrict__ Ws2,
                                                float* __restrict__ hs2,
                                                const float* __restrict__ Qs2,
                                                float* __restrict__ as2,
                                                const float* __restrict__ W3,
                                                unsigned short* __restrict__ w3hT,
                                                unsigned short* __restrict__ w3lT) {
    int idx = blockIdx.x * blockDim.x + threadIdx.x;
    if (idx < IN_A) {                       // conv1 message table, bf16
        int n = idx >> 7, j = idx & 127;
        float acc = 0.f;
        #pragma unroll
        for (int k = 0; k < 8; ++k) acc += x_data[n * 8 + k] * Ws1[k * 128 + j];
        hsb1[idx] = f2bf(acc);
    } else if (idx < IN_B) {                // as1
        int i = idx - IN_A;
        int n = i >> 2, h = i & 3;
        float acc = 0.f;
        #pragma unroll
        for (int k = 0; k < 8; ++k) acc += x_data[n * 8 + k] * Qs1[k * 4 + h];
        as1[i] = acc;
    } else if (idx < IN_C) {                // ad1, ad2 (one pass over x_tasks)
        int i = idx - IN_B;
        int n = i >> 2, h = i & 3;
        float a = 0.f, b = 0.f;
        #pragma unroll
        for (int k = 0; k < 16; ++k) {
            float v = x_tasks[n * 16 + k];
            a += v * Qd1[k * 4 + h];
            b += v * Qd2[k * 4 + h];
        }
        ad1[i] = a; ad2[i] = b;
    } else if (idx < IN_D) {                // hs2 (fp32)
        int i = idx - IN_C;
        int n = i >> 7, j = i & 127;
        float acc = 0.f;
        #pragma unroll
        for (int k = 0; k < 8; ++k) acc += x_dev[n * 8 + k] * Ws2[k * 128 + j];
        hs2[i] = acc;
    } else if (idx < IN_E) {                // as2
        int i = idx - IN_D;
        int n = i >> 2, h = i & 3;
        float acc = 0.f;
        #pragma unroll
        for (int k = 0; k < 8; ++k) acc += x_dev[n * 8 + k] * Qs2[k * 4 + h];
        as2[i] = acc;
    } else if (idx < IN_F) {                // W3 split, transposed
        int i = idx - IN_E;
        int k = i >> 7, n = i & 127;
        float x = W3[i];
        unsigned short h = f2bf(x);
        w3hT[n * 256 + k] = h;
        w3lT[n * 256 + k] = f2bf(x - bf2f(h));
    }
}

// degree histogram for all 3 graphs; also records each edge's rank within its dst
__global__ void k_hist(const int* __restrict__ dt, const int* __restrict__ vt,
                       const int* __restrict__ tt, int* __restrict__ deg,
                       int* __restrict__ rank) {
    int e = blockIdx.x * blockDim.x + threadIdx.x;
    if (e < EDT) rank[e] = atomicAdd(&deg[dt[EDT + e]], 1);
    else if (e < EDT + EVT) rank[e] = atomicAdd(&deg[NT + vt[EVT + (e - EDT)]], 1);
    else if (e < EDT + EVT + ETT) rank[e] = atomicAdd(&deg[2 * NT + tt[ETT + (e - EDT - EVT)]], 1);
}

// scan phase A: per-tile block reduce -> bsum[75]; coalesced int4 loads
__global__ __launch_bounds__(256) void k_scan_part(const int* __restrict__ deg,
                                                   int* __restrict__ bsum) {
    int b = blockIdx.x;
    int g = b / SCAN_NB, t = b % SCAN_NB;
    int base = t * SCAN_TILE + threadIdx.x * 8;
    const int* dg = deg + (size_t)g * NT;
    int s = 0;
    if (base + 8 <= NT) {
        int4 a = *reinterpret_cast<const int4*>(dg + base);
        int4 c = *reinterpret_cast<const int4*>(dg + base + 4);
        s = a.x + a.y + a.z + a.w + c.x + c.y + c.z + c.w;
    } else {
        for (int i = 0; i < 8; ++i) if (base + i < NT) s += dg[base + i];
    }
    __shared__ int red[256];
    red[threadIdx.x] = s;
    __syncthreads();
    for (int off = 128; off > 0; off >>= 1) {
        if (threadIdx.x < off) red[threadIdx.x] += red[threadIdx.x + off];
        __syncthreads();
    }
    if (threadIdx.x == 0) bsum[b] = red[0];
}

// scan phase B: one wave; exclusive-scan the 25 tile sums of each graph; write graph totals
__global__ void k_scan_bsum(int* __restrict__ bsum, int* __restrict__ rp) {
    int lane = threadIdx.x;
    for (int g = 0; g < 3; ++g) {
        int v = (lane < SCAN_NB) ? bsum[g * SCAN_NB + lane] : 0;
        int inc = v;
        #pragma unroll
        for (int off = 1; off < 32; off <<= 1) {
            int o = __shfl_up(inc, off, 32);
            if ((lane & 31) >= off) inc += o;
        }
        if (lane < SCAN_NB) bsum[g * SCAN_NB + lane] = inc - v;
        if (lane == SCAN_NB - 1) rp[(size_t)g * (NT + 1) + NT] = inc;
    }
}

// scan phase C: per-tile exclusive scan + tile offset; writes rp
__global__ __launch_bounds__(256) void k_scan_final(const int* __restrict__ deg,
                                                    const int* __restrict__ bsum,
                                                    int* __restrict__ rp) {
    int b = blockIdx.x;
    int g = b / SCAN_NB, t = b % SCAN_NB;
    int tid = threadIdx.x;
    int base = t * SCAN_TILE + tid * 8;
    const int* dg = deg + (size_t)g * NT;
    int* rpg = rp + (size_t)g * (NT + 1);
    int v[8];
    int s = 0;
    if (base + 8 <= NT) {
        int4 a = *reinterpret_cast<const int4*>(dg + base);
        int4 c = *reinterpret_cast<const int4*>(dg + base + 4);
        v[0] = a.x; v[1] = a.y; v[2] = a.z; v[3] = a.w;
        v[4] = c.x; v[5] = c.y; v[6] = c.z; v[7] = c.w;
        s = v[0] + v[1] + v[2] + v[3] + v[4] + v[5] + v[6] + v[7];
    } else {
        #pragma unroll
        for (int i = 0; i < 8; ++i) {
            v[i] = (base + i < NT) ? dg[base + i] : 0;
            s += v[i];
        }
    }
    __shared__ int sums[256];
    sums[tid] = s;
    __syncthreads();
    for (int off = 1; off < 256; off <<= 1) {
        int x = (tid >= off) ? sums[tid - off] : 0;
        __syncthreads();
        sums[tid] += x;
        __syncthreads();
    }
    int run = bsum[b] + (tid ? sums[tid - 1] : 0);
    #pragma unroll
    for (int i = 0; i < 8; ++i) {
        int idx = base + i;
        if (idx < NT) { rpg[idx] = run; run += v[i]; }
    }
}

// permute + weight precompute: ONE 16B scattered record per edge.
// conv1/conv2: {w0..w3 bf16 (8B), src, pad}; conv3: {src, ae0..ae3 bf16 (8B), pad}.
__global__ void k_permute_w(const int* __restrict__ dt, const int* __restrict__ vt,
                            const int* __restrict__ tt, const int* __restrict__ rank,
                            const int* __restrict__ rp,
                            const float* __restrict__ as1, const float* __restrict__ ad1,
                            const float* __restrict__ P1, const float* __restrict__ ea1,
                            const float* __restrict__ as2, const float* __restrict__ ad2,
                            const float* __restrict__ P2, const float* __restrict__ ea2,
                            const float* __restrict__ P3, const float* __restrict__ ea3,
                            uint4* __restrict__ rec1, uint4* __restrict__ rec2,
                            uint4* __restrict__ rec3) {
    int e = blockIdx.x * blockDim.x + threadIdx.x;
    if (e < EDT) {
        int s = dt[e], d = dt[EDT + e];
        int slot = rp[d] + rank[e];
        float l[4];
        #pragma unroll
        for (int h = 0; h < 4; ++h) l[h] = as1[s * 4 + h] + ad1[d * 4 + h];
        float4 A = *reinterpret_cast<const float4*>(&ea1[(size_t)e * 8]);
        float4 B = *reinterpret_cast<const float4*>(&ea1[(size_t)e * 8 + 4]);
        float ev[8] = {A.x, A.y, A.z, A.w, B.x, B.y, B.z, B.w};
        #pragma unroll
        for (int k = 0; k < 8; ++k)
            #pragma unroll
            for (int h = 0; h < 4; ++h) l[h] += ev[k] * P1[k * 4 + h];
        unsigned int w01 = (unsigned int)f2bf(expf(lrelu(l[0])))
                         | ((unsigned int)f2bf(expf(lrelu(l[1]))) << 16);
        unsigned int w23 = (unsigned int)f2bf(expf(lrelu(l[2])))
                         | ((unsigned int)f2bf(expf(lrelu(l[3]))) << 16);
        rec1[slot] = make_uint4(w01, w23, (unsigned int)s, 0u);
    } else if (e < EDT + EVT) {
        int ee = e - EDT;
        int s = vt[ee], d = vt[EVT + ee];
        int slot = rp[(NT + 1) + d] + rank[e];
        float l[4];
        #pragma unroll
        for (int h = 0; h < 4; ++h) l[h] = as2[s * 4 + h] + ad2[d * 4 + h];
        float2 a = *reinterpret_cast<const float2*>(&ea2[(size_t)ee * 6]);
        float2 b = *reinterpret_cast<const float2*>(&ea2[(size_t)ee * 6 + 2]);
        float2 c = *reinterpret_cast<const float2*>(&ea2[(size_t)ee * 6 + 4]);
        float ev[6] = {a.x, a.y, b.x, b.y, c.x, c.y};
        #pragma unroll
        for (int k = 0; k < 6; ++k)
            #pragma unroll
            for (int h = 0; h < 4; ++h) l[h] += ev[k] * P2[k * 4 + h];
        unsigned int w01 = (unsigned int)f2bf(expf(lrelu(l[0])))
                         | ((unsigned int)f2bf(expf(lrelu(l[1]))) << 16);
        unsigned int w23 = (unsigned int)f2bf(expf(lrelu(l[2])))
                         | ((unsigned int)f2bf(expf(lrelu(l[3]))) << 16);
        rec2[slot] = make_uint4(w01, w23, (unsigned int)s, 0u);
    } else if (e < EDT + EVT + ETT) {
        int ee = e - EDT - EVT;
        int s = tt[ee], d = tt[ETT + ee];
        int slot = rp[2 * (NT + 1) + d] + rank[e];
        float4 q = *reinterpret_cast<const float4*>(&ea3[(size_t)ee * 4]);
        float ae[4];
        #pragma unroll
        for (int h = 0; h < 4; ++h)
            ae[h] = q.x * P3[h] + q.y * P3[4 + h] + q.z * P3[8 + h] + q.w * P3[12 + h];
        unsigned int a01 = (unsigned int)f2bf(ae[0]) | ((unsigned int)f2bf(ae[1]) << 16);
        unsigned int a23 = (unsigned int)f2bf(ae[2]) | ((unsigned int)f2bf(ae[3]) << 16);
        rec3[slot] = make_uint4((unsigned int)s, a01, a23, 0u);
    }
}

// conv1 gather: sequential 16B records; only the 8B bf16 message load is random.
// 32 lanes/dst (head h=lane>>3, channels 4*(lane&7)..+3), unroll x4, bias+relu fused.
__global__ __launch_bounds__(256) void k_gather_c1(const int* __restrict__ rp,
                                                   const uint4* __restrict__ rec,
                                                   const unsigned short* __restrict__ hsb,
                                                   const float* __restrict__ bias,
                                                   float* __restrict__ tasks) {
    int tid = threadIdx.x;
    int d = blockIdx.x * 8 + (tid >> 5);
    int lane = tid & 31;
    int h = lane >> 3;
    int c0 = (lane & 7) * 4;
    int i0 = rp[d], i1 = rp[d + 1];
    float a0 = 0.f, a1 = 0.f, a2 = 0.f, a3 = 0.f, den = 0.f;
    int i = i0;
    for (; i + 4 <= i1; i += 4) {
        uint4 r0 = rec[i], r1 = rec[i + 1], r2 = rec[i + 2], r3 = rec[i + 3];
        float w0 = bfsel(r0.x, r0.y, h);
        float w1 = bfsel(r1.x, r1.y, h);
        float w2 = bfsel(r2.x, r2.y, h);
        float w3 = bfsel(r3.x, r3.y, h);
        ushort4 m0 = *reinterpret_cast<const ushort4*>(&hsb[(size_t)r0.z * 128 + h * 32 + c0]);
        ushort4 m1 = *reinterpret_cast<const ushort4*>(&hsb[(size_t)r1.z * 128 + h * 32 + c0]);
        ushort4 m2 = *reinterpret_cast<const ushort4*>(&hsb[(size_t)r2.z * 128 + h * 32 + c0]);
        ushort4 m3 = *reinterpret_cast<const ushort4*>(&hsb[(size_t)r3.z * 128 + h * 32 + c0]);
        a0 += w0 * bf2f(m0.x) + w1 * bf2f(m1.x) + w2 * bf2f(m2.x) + w3 * bf2f(m3.x);
        a1 += w0 * bf2f(m0.y) + w1 * bf2f(m1.y) + w2 * bf2f(m2.y) + w3 * bf2f(m3.y);
        a2 += w0 * bf2f(m0.z) + w1 * bf2f(m1.z) + w2 * bf2f(m2.z) + w3 * bf2f(m3.z);
        a3 += w0 * bf2f(m0.w) + w1 * bf2f(m1.w) + w2 * bf2f(m2.w) + w3 * bf2f(m3.w);
        den += w0 + w1 + w2 + w3;
    }
    for (; i < i1; ++i) {
        uint4 r = rec[i];
        float w = bfsel(r.x, r.y, h);
        ushort4 m = *reinterpret_cast<const ushort4*>(&hsb[(size_t)r.z * 128 + h * 32 + c0]);
        a0 += w * bf2f(m.x); a1 += w * bf2f(m.y);
        a2 += w * bf2f(m.z); a3 += w * bf2f(m.w);
        den += w;
    }
    int j0 = h * 32 + c0;
    float4 b4 = *reinterpret_cast<const float4*>(&bias[j0]);
    float r = 1.f / (den + 1e-16f);
    float4 o = make_float4(fmaxf(a0 * r + b4.x, 0.f), fmaxf(a1 * r + b4.y, 0.f),
                           fmaxf(a2 * r + b4.z, 0.f), fmaxf(a3 * r + b4.w, 0.f));
    *reinterpret_cast<float4*>(&tasks[(size_t)d * 256 + j0]) = o;
}

// conv2 gather: sequential 16B records; message table 2KB fp32 (cache-resident)
__global__ __launch_bounds__(256) void k_gather_c2(const int* __restrict__ rp,
                                                   const uint4* __restrict__ rec,
                                                   const float* __restrict__ hs2,
                                                   const float* __restrict__ bias,
                                                   float* __restrict__ tasks) {
    int tid = threadIdx.x;
    int d = blockIdx.x * 8 + (tid >> 5);
    int lane = tid & 31;
    int h = lane >> 3;
    int i0 = rp[d], i1 = rp[d + 1];
    float ax = 0.f, ay = 0.f, az = 0.f, aw = 0.f, den = 0.f;
    int i = i0;
    for (; i + 4 <= i1; i += 4) {
        uint4 r0 = rec[i], r1 = rec[i + 1], r2 = rec[i + 2], r3 = rec[i + 3];
        float w0 = bfsel(r0.x, r0.y, h);
        float w1 = bfsel(r1.x, r1.y, h);
        float w2 = bfsel(r2.x, r2.y, h);
        float w3 = bfsel(r3.x, r3.y, h);
        float4 v0 = *reinterpret_cast<const float4*>(&hs2[r0.z * 128 + lane * 4]);
        float4 v1 = *reinterpret_cast<const float4*>(&hs2[r1.z * 128 + lane * 4]);
        float4 v2 = *reinterpret_cast<const float4*>(&hs2[r2.z * 128 + lane * 4]);
        float4 v3 = *reinterpret_cast<const float4*>(&hs2[r3.z * 128 + lane * 4]);
        ax += v0.x * w0 + v1.x * w1 + v2.x * w2 + v3.x * w3;
        ay += v0.y * w0 + v1.y * w1 + v2.y * w2 + v3.y * w3;
        az += v0.z * w0 + v1.z * w1 + v2.z * w2 + v3.z * w3;
        aw += v0.w * w0 + v1.w * w1 + v2.w * w2 + v3.w * w3;
        den += w0 + w1 + w2 + w3;
    }
    for (; i < i1; ++i) {
        uint4 r4 = rec[i];
        float w = bfsel(r4.x, r4.y, h);
        float4 v = *reinterpret_cast<const float4*>(&hs2[r4.z * 128 + lane * 4]);
        ax += v.x * w; ay += v.y * w; az += v.z * w; aw += v.w * w;
        den += w;
    }
    float4 b4 = *reinterpret_cast<const float4*>(&bias[lane * 4]);
    float r = 1.f / (den + 1e-16f);
    float4 o = make_float4(fmaxf(ax * r + b4.x, 0.f), fmaxf(ay * r + b4.y, 0.f),
                           fmaxf(az * r + b4.z, 0.f), fmaxf(aw * r + b4.w, 0.f));
    *reinterpret_cast<float4*>(&tasks[(size_t)d * 256 + 128 + lane * 4]) = o;
}

// fused: as3/ad3 from one float4-vectorized pass over hs3; also emits bf16 copy hsb
__global__ void k_alpha_from_h2(const float* __restrict__ hs, const float* __restrict__ As,
                                const float* __restrict__ Ad, float* __restrict__ oa,
                                float* __restrict__ ob, unsigned short* __restrict__ hsb,
                                int N) {
    int idx = blockIdx.x * blockDim.x + threadIdx.x;
    if (idx >= N * 4) return;
    int n = idx >> 2, h = idx & 3;
    const float* row = hs + (size_t)n * 128 + h * 32;
    unsigned short* brow = hsb + (size_t)n * 128 + h * 32;
    float a = 0.f, b = 0.f;
    #pragma unroll
    for (int c = 0; c < 32; c += 4) {
        float4 v = *reinterpret_cast<const float4*>(row + c);
        a += v.x * As[h * 32 + c]     + v.y * As[h * 32 + c + 1]
           + v.z * As[h * 32 + c + 2] + v.w * As[h * 32 + c + 3];
        b += v.x * Ad[h * 32 + c]     + v.y * Ad[h * 32 + c + 1]
           + v.z * Ad[h * 32 + c + 2] + v.w * Ad[h * 32 + c + 3];
        ushort4 pk;
        pk.x = f2bf(v.x); pk.y = f2bf(v.y); pk.z = f2bf(v.z); pk.w = f2bf(v.w);
        *reinterpret_cast<ushort4*>(brow + c) = pk;
    }
    oa[idx] = a; ob[idx] = b;
}

// conv3 gather: 16B records carry {src, ae bf16}; per-head softmax + self-loop
// (mean ae); head-mean via shfl_xor; +b3, relu fused. Writes d_out once.
__global__ __launch_bounds__(256) void k_gather_c3(const int* __restrict__ rp,
                                                   const uint4* __restrict__ rec,
                                                   const float* __restrict__ as3,
                                                   const float* __restrict__ ad3,
                                                   const unsigned short* __restrict__ hsb,
                                                   const float* __restrict__ b3,
                                                   float* __restrict__ out) {
    int tid = threadIdx.x;
    int d = blockIdx.x * 8 + (tid >> 5);
    int lane = tid & 31;
    int h = lane >> 3;
    int c0 = (lane & 7) * 4;
    float adv = ad3[d * 4 + h];
    int i0 = rp[d], i1 = rp[d + 1];
    float a0 = 0.f, a1 = 0.f, a2 = 0.f, a3 = 0.f, den = 0.f, aes = 0.f;
    int i = i0;
    for (; i + 4 <= i1; i += 4) {
        uint4 r0 = rec[i], r1 = rec[i + 1], r2 = rec[i + 2], r3 = rec[i + 3];
        float s0 = as3[(size_t)r0.x * 4 + h], s1 = as3[(size_t)r1.x * 4 + h];
        float s2 = as3[(size_t)r2.x * 4 + h], s3 = as3[(size_t)r3.x * 4 + h];
        ushort4 m0 = *reinterpret_cast<const ushort4*>(&hsb[(size_t)r0.x * 128 + h * 32 + c0]);
        ushort4 m1 = *reinterpret_cast<const ushort4*>(&hsb[(size_t)r1.x * 128 + h * 32 + c0]);
        ushort4 m2 = *reinterpret_cast<const ushort4*>(&hsb[(size_t)r2.x * 128 + h * 32 + c0]);
        ushort4 m3 = *reinterpret_cast<const ushort4*>(&hsb[(size_t)r3.x * 128 + h * 32 + c0]);
        float ae0 = bfsel(r0.y, r0.z, h);
        float ae1 = bfsel(r1.y, r1.z, h);
        float ae2 = bfsel(r2.y, r2.z, h);
        float ae3 = bfsel(r3.y, r3.z, h);
        float w0 = expf(lrelu(s0 + adv + ae0));
        float w1 = expf(lrelu(s1 + adv + ae1));
        float w2 = expf(lrelu(s2 + adv + ae2));
        float w3 = expf(lrelu(s3 + adv + ae3));
        a0 += w0 * bf2f(m0.x) + w1 * bf2f(m1.x) + w2 * bf2f(m2.x) + w3 * bf2f(m3.x);
        a1 += w0 * bf2f(m0.y) + w1 * bf2f(m1.y) + w2 * bf2f(m2.y) + w3 * bf2f(m3.y);
        a2 += w0 * bf2f(m0.z) + w1 * bf2f(m1.z) + w2 * bf2f(m2.z) + w3 * bf2f(m3.z);
        a3 += w0 * bf2f(m0.w) + w1 * bf2f(m1.w) + w2 * bf2f(m2.w) + w3 * bf2f(m3.w);
        den += w0 + w1 + w2 + w3;
        aes += ae0 + ae1 + ae2 + ae3;
    }
    for (; i < i1; ++i) {
        uint4 r4 = rec[i];
        float s = as3[(size_t)r4.x * 4 + h];
        ushort4 m = *reinterpret_cast<const ushort4*>(&hsb[(size_t)r4.x * 128 + h * 32 + c0]);
        float ae = bfsel(r4.y, r4.z, h);
        float w = expf(lrelu(s + adv + ae));
        a0 += w * bf2f(m.x); a1 += w * bf2f(m.y);
        a2 += w * bf2f(m.z); a3 += w * bf2f(m.w);
        den += w; aes += ae;
    }
    float cnt = (float)(i1 - i0);
    float mloop = aes / fmaxf(cnt, 1.f);
    float exl = expf(lrelu(as3[(size_t)d * 4 + h] + adv + mloop));
    ushort4 md = *reinterpret_cast<const ushort4*>(&hsb[(size_t)d * 128 + h * 32 + c0]);
    float rden = 1.f / (den + exl + 1e-16f);
    float p0 = (a0 + exl * bf2f(md.x)) * rden;
    float p1 = (a1 + exl * bf2f(md.y)) * rden;
    float p2 = (a2 + exl * bf2f(md.z)) * rden;
    float p3 = (a3 + exl * bf2f(md.w)) * rden;
    p0 += __shfl_xor(p0, 8, 32); p0 += __shfl_xor(p0, 16, 32);
    p1 += __shfl_xor(p1, 8, 32); p1 += __shfl_xor(p1, 16, 32);
    p2 += __shfl_xor(p2, 8, 32); p2 += __shfl_xor(p2, 16, 32);
    p3 += __shfl_xor(p3, 8, 32); p3 += __shfl_xor(p3, 16, 32);
    if ((lane >> 3) == 0) {
        float4 o;
        o.x = fmaxf(0.25f * p0 + b3[c0 + 0], 0.f);
        o.y = fmaxf(0.25f * p1 + b3[c0 + 1], 0.f);
        o.z = fmaxf(0.25f * p2 + b3[c0 + 2], 0.f);
        o.w = fmaxf(0.25f * p3 + b3[c0 + 3], 0.f);
        *reinterpret_cast<float4*>(&out[(size_t)d * 32 + c0]) = o;
    }
}

// hs3 = tasks[50000,256] @ W3[256,128] via bf16 split MFMA (Ah*Bh + Ah*Bl + Al*Bh)
__global__ __launch_bounds__(256, 2) void k_gemm_mfma(const float* __restrict__ T,
                                                      const unsigned short* __restrict__ w3hT,
                                                      const unsigned short* __restrict__ w3lT,
                                                      float* __restrict__ outp) {
    __shared__ uint4 sB[2][2048];      // [hi/lo][128 cols x 16 chunks], 64 KiB
    int tid = threadIdx.x;
    int lane = tid & 63;
    int wid = tid >> 6;
    int arow = lane & 15;
    int kgrp = lane >> 4;
    int s0 = blockIdx.x * 8 + wid * 2;
    int ss0 = s0 < 3125 ? s0 : 3124;
    int ss1 = (s0 + 1) < 3125 ? (s0 + 1) : 3124;
    const uint4* w3h4 = reinterpret_cast<const uint4*>(w3hT);
    const uint4* w3l4 = reinterpret_cast<const uint4*>(w3lT);

    v4f acc[2][8];
    #pragma unroll
    for (int sp = 0; sp < 2; ++sp)
        #pragma unroll
        for (int nt = 0; nt < 8; ++nt) acc[sp][nt] = (v4f)0.f;

    #pragma unroll
    for (int kt = 0; kt < 2; ++kt) {
        __syncthreads();
        float4 a0[8], a1[8];
        const float* Ta0 = T + (size_t)(ss0 * 16 + arow) * 256 + kt * 128 + kgrp * 8;
        const float* Ta1 = T + (size_t)(ss1 * 16 + arow) * 256 + kt * 128 + kgrp * 8;
        #pragma unroll
        for (int kc = 0; kc < 4; ++kc) {
            a0[kc * 2]     = *reinterpret_cast<const float4*>(Ta0 + kc * 32);
            a0[kc * 2 + 1] = *reinterpret_cast<const float4*>(Ta0 + kc * 32 + 4);
            a1[kc * 2]     = *reinterpret_cast<const float4*>(Ta1 + kc * 32);
            a1[kc * 2 + 1] = *reinterpret_cast<const float4*>(Ta1 + kc * 32 + 4);
        }
        #pragma unroll
        for (int it = 0; it < 8; ++it) {
            int c = it * 256 + tid;
            int n = c >> 4, ch = c & 15;
            int gi = n * 32 + kt * 16 + ch;
            int li = n * 16 + (ch ^ (n & 7));
            sB[0][li] = w3h4[gi];
            sB[1][li] = w3l4[gi];
        }
        __syncthreads();
        #pragma unroll
        for (int kc = 0; kc < 4; ++kc) {
            v8s ah0, al0, ah1, al1;
            cvt_split(a0[kc * 2], a0[kc * 2 + 1], ah0, al0);
            cvt_split(a1[kc * 2], a1[kc * 2 + 1], ah1, al1);
            #pragma unroll
            for (int nt = 0; nt < 8; ++nt) {
                int col = nt * 16 + arow;
                int ch = kc * 4 + kgrp;
                int li = col * 16 + (ch ^ (col & 7));
                v8s bh = *reinterpret_cast<const v8s*>(&sB[0][li]);
                v8s bl = *reinterpret_cast<const v8s*>(&sB[1][li]);
                acc[0][nt] = __builtin_amdgcn_mfma_f32_16x16x32_bf16(ah0, bh, acc[0][nt], 0, 0, 0);
                acc[0][nt] = __builtin_amdgcn_mfma_f32_16x16x32_bf16(ah0, bl, acc[0][nt], 0, 0, 0);
                acc[0][nt] = __builtin_amdgcn_mfma_f32_16x16x32_bf16(al0, bh, acc[0][nt], 0, 0, 0);
                acc[1][nt] = __builtin_amdgcn_mfma_f32_16x16x32_bf16(ah1, bh, acc[1][nt], 0, 0, 0);
                acc[1][nt] = __builtin_amdgcn_mfma_f32_16x16x32_bf16(ah1, bl, acc[1][nt], 0, 0, 0);
                acc[1][nt] = __builtin_amdgcn_mfma_f32_16x16x32_bf16(al1, bh, acc[1][nt], 0, 0, 0);
            }
        }
    }
    if (s0 < 3125) {
        #pragma unroll
        for (int nt = 0; nt < 8; ++nt)
            #pragma unroll
            for (int i = 0; i < 4; ++i)
                outp[(size_t)(s0 * 16 + kgrp * 4 + i) * 128 + nt * 16 + arow] = acc[0][nt][i];
    }
    if (s0 + 1 < 3125) {
        #pragma unroll
        for (int nt = 0; nt < 8; ++nt)
            #pragma unroll
            for (int i = 0; i < 4; ++i)
                outp[(size_t)((s0 + 1) * 16 + kgrp * 4 + i) * 128 + nt * 16 + arow] = acc[1][nt][i];
    }
}

extern "C" void kernel_launch(void* const* d_in, const int* in_sizes, int n_in,
                              void* d_out, int out_size, void* d_ws, size_t ws_size,
                              hipStream_t stream) {
    const float* x_data  = (const float*)d_in[0];
    const float* x_tasks = (const float*)d_in[1];
    const float* x_dev   = (const float*)d_in[2];
    const int*   ei_dt   = (const int*)d_in[3];
    const float* ea_dt   = (const float*)d_in[4];
    const int*   ei_vt   = (const int*)d_in[5];
    const float* ea_vt   = (const float*)d_in[6];
    const int*   ei_tt   = (const int*)d_in[7];
    const float* ea_tt   = (const float*)d_in[8];
    const float* Ws1 = (const float*)d_in[9];  const float* Wd1 = (const float*)d_in[10];
    const float* We1 = (const float*)d_in[11]; const float* As1 = (const float*)d_in[12];
    const float* Ad1 = (const float*)d_in[13]; const float* Ae1 = (const float*)d_in[14];
    const float* b1  = (const float*)d_in[15];
    const float* Ws2 = (const float*)d_in[16]; const float* Wd2 = (const float*)d_in[17];
    const float* We2 = (const float*)d_in[18]; const float* As2 = (const float*)d_in[19];
    const float* Ad2 = (const float*)d_in[20]; const float* Ae2 = (const float*)d_in[21];
    const float* b2  = (const float*)d_in[22];
    const float* W3  = (const float*)d_in[23]; const float* We3 = (const float*)d_in[24];
    const float* As3 = (const float*)d_in[25]; const float* Ad3 = (const float*)d_in[26];
    const float* Ae3 = (const float*)d_in[27]; const float* b3  = (const float*)d_in[28];

    if (ws_size < WS_TOTAL * sizeof(float)) return;

    float* w = (float*)d_ws;
    float* tasks = w + OFF_TASKS;
    unsigned short* hsb3 = (unsigned short*)(w + OFF_TASKS);  // aliases tasks (dead after gemm)
    float* hs    = w + OFF_HS;                                // hs3 (written by gemm)
    int*   rank  = (int*)(w + OFF_RANK);
    unsigned short* hsb1 = (unsigned short*)(w + OFF_HSB1);
    uint4* rec1  = (uint4*)(w + OFF_REC1);
    uint4* rec2  = (uint4*)(w + OFF_REC2);
    uint4* rec3  = (uint4*)(w + OFF_REC3);
    int*   deg   = (int*)(w + OFF_DEG);
    int*   rp    = (int*)(w + OFF_RP);
    int*   bsum  = (int*)(w + OFF_BSUM);
    unsigned short* w3hT = (unsigned short*)(w + OFF_W3HT);
    unsigned short* w3lT = (unsigned short*)(w + OFF_W3LT);
    float* as1 = w + OFF_AS1;
    float* ad1 = w + OFF_AD1; float* as3 = w + OFF_AD1;   // as3 aliases ad1
    float* ad2 = w + OFF_AD2; float* ad3 = w + OFF_AD2;   // ad3 aliases ad2
    float* hs2 = w + OFF_HS2; float* as2 = w + OFF_AS2;
    float* Qs1 = w + OFF_QS1; float* Qd1 = w + OFF_QD1; float* P1 = w + OFF_P1;
    float* Qs2 = w + OFF_QS2; float* Qd2 = w + OFF_QD2; float* P2 = w + OFF_P2;
    float* P3  = w + OFF_P3;
    float* out = (float*)d_out;

    dim3 B(256);
    #define GRID(n) dim3((unsigned)(((n) + 255) / 256))

    hipMemsetAsync(deg, 0, 3 * NT * sizeof(int), stream);
    k_proj_small<<<1, 320, 0, stream>>>(Ws1, As1, Wd1, Ad1, We1, Ae1,
                                        Ws2, As2, Wd2, Ad2, We2, Ae2, We3, Ae3,
                                        Qs1, Qd1, P1, Qs2, Qd2, P2, P3);
    k_inputs<<<GRID(IN_F), B, 0, stream>>>(x_data, Ws1, hsb1, Qs1, as1,
                                           x_tasks, Qd1, Qd2, ad1, ad2,
                                           x_dev, Ws2, hs2, Qs2, as2,
                                           W3, w3hT, w3lT);
    k_hist<<<GRID(EDT + EVT + ETT), B, 0, stream>>>(ei_dt, ei_vt, ei_tt, deg, rank);
    k_scan_part<<<dim3(3 * SCAN_NB), B, 0, stream>>>(deg, bsum);
    k_scan_bsum<<<1, 64, 0, stream>>>(bsum, rp);
    k_scan_final<<<dim3(3 * SCAN_NB), B, 0, stream>>>(deg, bsum, rp);
    k_permute_w<<<GRID(EDT + EVT + ETT), B, 0, stream>>>(ei_dt, ei_vt, ei_tt, rank, rp,
                                                         as1, ad1, P1, ea_dt,
                                                         as2, ad2, P2, ea_vt,
                                                         P3, ea_tt,
                                                         rec1, rec2, rec3);
    // gathers (bias+relu fused; single 16B sequential record stream per edge)
    k_gather_c1<<<dim3(NT / 8), B, 0, stream>>>(rp, rec1, hsb1, b1, tasks);
    k_gather_c2<<<dim3(NT / 8), B, 0, stream>>>(rp + (NT + 1), rec2, hs2, b2, tasks);

    // conv3: tasks -> tasks
    k_gemm_mfma<<<dim3(391), dim3(256), 0, stream>>>(tasks, w3hT, w3lT, hs);
    k_alpha_from_h2<<<GRID(NT * 4), B, 0, stream>>>(hs, As3, Ad3, as3, ad3, hsb3, NT);
    k_gather_c3<<<dim3(NT / 8), B, 0, stream>>>(rp + 2 * (NT + 1), rec3, as3, ad3,
                                                hsb3, b3, out);
    #undef GRID
}